// Round 3
// baseline (3364.445 us; speedup 1.0000x reference)
//
#include <hip/hip_runtime.h>
#include <hip/hip_bf16.h>
#include <hip/hip_cooperative_groups.h>

namespace cg = cooperative_groups;

// ---------------- problem constants ----------------
constexpr int GT = 32768;          // B*T frames
constexpr int TSEQ = 32;

// ---------------- workspace layout (floats) ----------------
// R0 [0, 13107200): obsT [400][GT]; reused: pool2 [128][GT]@0, y1 [128][GT]@4194304;
//                   after fc2 reused again: gates_x slices t=0..24 (25 x 524288 = 13107200 exactly)
// R1 [13107200, 26214400): pool1 [400][GT]; reused: featsT [64][GT]@13107200,
//                   gates_x slices t=25..31 @ 15204352 (7 x 524288 = 3670016)
constexpr size_t OBS_T = 0;
constexpr size_t POOL1 = 13107200;
constexpr size_t POOL2 = 0;
constexpr size_t Y1    = 4194304;
constexpr size_t FEATS = 13107200;
constexpr size_t GX0   = 0;                 // t<25
constexpr size_t GX1   = 15204352;          // t>=25
constexpr size_t WB    = 26214400;          // weights region
constexpr size_t W_C1  = WB + 0;            // 576   : conv1 wT [36][16]
constexpr size_t W_C2  = WB + 576;          // 4608  : conv2 wT [144][32]
constexpr size_t W_F1  = WB + 5184;         // 16384 : fc1 wT [128][128], BN folded
constexpr size_t B_F1  = WB + 21568;        // 128
constexpr size_t W_F2  = WB + 21696;        // 8192  : fc2 wT [128][64], BN folded
constexpr size_t B_F2  = WB + 29888;        // 64
constexpr size_t W_ENC = WB + 29952;        // 98304 : enc wT [192][512], rows r=u*4+gate
constexpr size_t B_ENC = WB + 128256;       // 512
constexpr size_t W_DEC = WB + 128768;       // 65536 : (dec_w_ih+dec_w_hh) wT [128][512]
constexpr size_t B_DEC = WB + 194304;       // 512
constexpr size_t HA    = WB + 194816;       // 131072 : h ping
constexpr size_t HB    = HA + 131072;       // 131072 : h pong
constexpr size_t CC    = HB + 131072;       // 131072 : c state
// total = 26,802,432 floats = ~107.2 MB

__device__ __forceinline__ float sigf(float x)  { return 1.f / (1.f + __expf(-x)); }
__device__ __forceinline__ float tanhfast(float x) { return 1.f - 2.f / (__expf(2.f * x) + 1.f); }

// ---------------- setup: zero state + transpose/fold weights ----------------
__global__ __launch_bounds__(256) void k_setup(
    const float* __restrict__ c1w, const float* __restrict__ c2w,
    const float* __restrict__ f1w, const float* __restrict__ f1b,
    const float* __restrict__ g1, const float* __restrict__ be1,
    const float* __restrict__ m1, const float* __restrict__ v1,
    const float* __restrict__ f2w, const float* __restrict__ f2b,
    const float* __restrict__ g2, const float* __restrict__ be2,
    const float* __restrict__ m2, const float* __restrict__ v2,
    const float* __restrict__ ewih, const float* __restrict__ ewhh, const float* __restrict__ eb,
    const float* __restrict__ dwih, const float* __restrict__ dwhh, const float* __restrict__ db,
    float* __restrict__ ws) {
  long i = (long)blockIdx.x * 256 + threadIdx.x;
  if (i < 393216) { ws[HA + i] = 0.f; return; }          // zero hA, hB, c
  i -= 393216;
  if (i < 576)  { int c = i & 15, r = i >> 4; ws[W_C1 + i] = c1w[c * 36 + r]; return; }
  i -= 576;
  if (i < 4608) { int c = i & 31, r = i >> 5; ws[W_C2 + i] = c2w[c * 144 + r]; return; }
  i -= 4608;
  if (i < 16384) { int j = i & 127, k = i >> 7;
    float s = g1[j] * rsqrtf(v1[j] + 1e-5f);
    ws[W_F1 + i] = f1w[j * 128 + k] * s; return; }
  i -= 16384;
  if (i < 128) { int j = i; float s = g1[j] * rsqrtf(v1[j] + 1e-5f);
    ws[B_F1 + i] = (f1b[j] - m1[j]) * s + be1[j]; return; }
  i -= 128;
  if (i < 8192) { int j = i & 63, k = i >> 6;
    float s = g2[j] * rsqrtf(v2[j] + 1e-5f);
    ws[W_F2 + i] = f2w[j * 128 + k] * s; return; }
  i -= 8192;
  if (i < 64) { int j = i; float s = g2[j] * rsqrtf(v2[j] + 1e-5f);
    ws[B_F2 + i] = (f2b[j] - m2[j]) * s + be2[j]; return; }
  i -= 64;
  if (i < 98304) { int r = i & 511, k = i >> 9;
    int u = r >> 2, gt = r & 3, jr = gt * 128 + u;
    ws[W_ENC + i] = (k < 64) ? ewih[jr * 64 + k] : ewhh[jr * 128 + (k - 64)]; return; }
  i -= 98304;
  if (i < 512) { int u = i >> 2, gt = i & 3; ws[B_ENC + i] = eb[gt * 128 + u]; return; }
  i -= 512;
  if (i < 65536) { int r = i & 511, k = i >> 9;
    int u = r >> 2, gt = r & 3, jr = gt * 128 + u;
    ws[W_DEC + i] = dwih[jr * 128 + k] + dwhh[jr * 128 + k]; return; }
  i -= 65536;
  if (i < 512) { int u = i >> 2, gt = i & 3; ws[B_DEC + i] = db[gt * 128 + u]; return; }
}

// ---------------- transpose obs [b][tp] -> obsT [p][t][b], float4 loads ----------------
__global__ __launch_bounds__(256) void k_transpose(const float* __restrict__ obs,
                                                   float* __restrict__ obsT) {
  __shared__ float tile[64][65];
  int tp0 = blockIdx.x * 64;        // 200 tiles over tp=12800
  int b0  = blockIdx.y * 64;        // 16 tiles over b=1024
  int q     = threadIdx.x & 15;     // tp quad
  int rbase = threadIdx.x >> 4;     // 0..15
  #pragma unroll
  for (int rr = 0; rr < 4; ++rr) {
    int row = rbase + rr * 16;      // b_local 0..63
    const float4 v = *(const float4*)(obs + (size_t)(b0 + row) * 12800 + tp0 + q * 4);
    tile[row][q * 4 + 0] = v.x;
    tile[row][q * 4 + 1] = v.y;
    tile[row][q * 4 + 2] = v.z;
    tile[row][q * 4 + 3] = v.w;
  }
  __syncthreads();
  int lane = threadIdx.x & 63;
  int grp  = threadIdx.x >> 6;      // 0..3
  for (int cc = 0; cc < 16; ++cc) {
    int col = grp * 16 + cc;        // tp_local
    int tp = tp0 + col;
    int t = tp / 400, p = tp % 400;
    obsT[(size_t)p * GT + t * 1024 + b0 + lane] = tile[lane][col];
  }
}

// ---------------- conv1 (4->16, 3x3 SAME on 10x10) + relu + maxpool2 ----------------
__global__ __launch_bounds__(256) void k_conv1(const float* __restrict__ obsT,
                                               const float* __restrict__ wT,
                                               const float* __restrict__ bias,
                                               float* __restrict__ pool1) {
  int g = blockIdx.x * 256 + threadIdx.x;
  int pos = blockIdx.y;                 // 0..24 pooled position
  int py = pos / 5, px = pos % 5;
  float acc[4][16];
  #pragma unroll
  for (int s = 0; s < 4; ++s)
    #pragma unroll
    for (int c = 0; c < 16; ++c) acc[s][c] = 0.f;

  #pragma unroll 1
  for (int ci = 0; ci < 4; ++ci) {
    float p[16];
    #pragma unroll
    for (int r = 0; r < 4; ++r) {
      int iy = 2 * py + r - 1;
      #pragma unroll
      for (int cx = 0; cx < 4; ++cx) {
        int ix = 2 * px + cx - 1;
        bool ok = ((unsigned)iy < 10u) && ((unsigned)ix < 10u);   // wave-uniform
        p[r * 4 + cx] = ok ? obsT[(size_t)(ci * 100 + iy * 10 + ix) * GT + g] : 0.f;
      }
    }
    #pragma unroll
    for (int t9 = 0; t9 < 9; ++t9) {
      int ky = t9 / 3, kx = t9 % 3;
      const float* w = wT + ((ci * 9 + t9) << 4);
      float wv[16];
      #pragma unroll
      for (int c = 0; c < 16; ++c) wv[c] = w[c];
      #pragma unroll
      for (int dy = 0; dy < 2; ++dy)
        #pragma unroll
        for (int dx = 0; dx < 2; ++dx) {
          float xv = p[(dy + ky) * 4 + (dx + kx)];
          #pragma unroll
          for (int c = 0; c < 16; ++c)
            acc[dy * 2 + dx][c] = fmaf(wv[c], xv, acc[dy * 2 + dx][c]);
        }
    }
  }
  #pragma unroll
  for (int c = 0; c < 16; ++c) {
    float m = fmaxf(fmaxf(acc[0][c], acc[1][c]), fmaxf(acc[2][c], acc[3][c]));
    m = fmaxf(m + bias[c], 0.f);
    pool1[(size_t)(c * 25 + pos) * GT + g] = m;
  }
}

// ---------------- conv2 (16->32, 3x3 SAME on 5x5) + relu + maxpool2(floor) ----------------
__global__ __launch_bounds__(256) void k_conv2(const float* __restrict__ pool1,
                                               const float* __restrict__ wT,
                                               const float* __restrict__ bias,
                                               float* __restrict__ pool2) {
  int g = blockIdx.x * 256 + threadIdx.x;
  int pos = blockIdx.y & 3;             // pooled pos (2x2)
  int h = blockIdx.y >> 2;              // c_out half
  int py = pos >> 1, px = pos & 1;
  float acc[4][16];
  #pragma unroll
  for (int s = 0; s < 4; ++s)
    #pragma unroll
    for (int c = 0; c < 16; ++c) acc[s][c] = 0.f;

  #pragma unroll 1
  for (int ci = 0; ci < 16; ++ci) {
    float p[16];
    #pragma unroll
    for (int r = 0; r < 4; ++r) {
      int iy = 2 * py + r - 1;
      #pragma unroll
      for (int cx = 0; cx < 4; ++cx) {
        int ix = 2 * px + cx - 1;
        bool ok = ((unsigned)iy < 5u) && ((unsigned)ix < 5u);     // wave-uniform
        p[r * 4 + cx] = ok ? pool1[(size_t)(ci * 25 + iy * 5 + ix) * GT + g] : 0.f;
      }
    }
    #pragma unroll
    for (int t9 = 0; t9 < 9; ++t9) {
      int ky = t9 / 3, kx = t9 % 3;
      const float* w = wT + (ci * 9 + t9) * 32 + h * 16;
      float wv[16];
      #pragma unroll
      for (int c = 0; c < 16; ++c) wv[c] = w[c];
      #pragma unroll
      for (int dy = 0; dy < 2; ++dy)
        #pragma unroll
        for (int dx = 0; dx < 2; ++dx) {
          float xv = p[(dy + ky) * 4 + (dx + kx)];
          #pragma unroll
          for (int c = 0; c < 16; ++c)
            acc[dy * 2 + dx][c] = fmaf(wv[c], xv, acc[dy * 2 + dx][c]);
        }
    }
  }
  #pragma unroll
  for (int c = 0; c < 16; ++c) {
    float m = fmaxf(fmaxf(acc[0][c], acc[1][c]), fmaxf(acc[2][c], acc[3][c]));
    m = fmaxf(m + bias[h * 16 + c], 0.f);
    int cp2 = (h * 16 + c) * 4 + pos;   // torch NCHW flatten: c*4 + py*2 + px
    pool2[(size_t)cp2 * GT + g] = m;
  }
}

// ---------------- FC (+folded BN) + relu, 16 outputs/thread ----------------
__global__ __launch_bounds__(256) void k_fc16(const float* __restrict__ x,
                                              const float* __restrict__ WT,
                                              const float* __restrict__ bf,
                                              float* __restrict__ y, int K, int J) {
  int g = blockIdx.x * 256 + threadIdx.x;
  int j0 = blockIdx.y * 16;
  float acc[16];
  #pragma unroll
  for (int c = 0; c < 16; ++c) acc[c] = 0.f;
  for (int k = 0; k < K; ++k) {
    float xv = x[(size_t)k * GT + g];
    const float* w = WT + (size_t)k * J + j0;
    #pragma unroll
    for (int c = 0; c < 16; ++c) acc[c] = fmaf(w[c], xv, acc[c]);
  }
  #pragma unroll
  for (int c = 0; c < 16; ++c)
    y[(size_t)(j0 + c) * GT + g] = fmaxf(acc[c] + bf[j0 + c], 0.f);
}

// ---------------- encoder x-projection for ALL timesteps (parallel, bias folded) ----
__global__ __launch_bounds__(256) void k_xgates(const float* __restrict__ feats,
                                                const float* __restrict__ WT,
                                                const float* __restrict__ br,
                                                float* __restrict__ gx0,
                                                float* __restrict__ gx1) {
  int t  = blockIdx.x >> 2;
  int bq = blockIdx.x & 3;
  int b  = bq * 256 + threadIdx.x;
  int r0 = blockIdx.y * 32;
  float acc[32];
  #pragma unroll
  for (int i = 0; i < 32; ++i) acc[i] = br[r0 + i];
  const float* xcol = feats + (size_t)t * 1024 + b;
  for (int k = 0; k < 64; ++k) {
    float xv = xcol[(size_t)k * GT];
    const float* w = WT + k * 512 + r0;
    #pragma unroll
    for (int i = 0; i < 32; ++i) acc[i] = fmaf(w[i], xv, acc[i]);
  }
  float* gxs = (t < 25) ? (gx0 + (size_t)t * 524288)
                        : (gx1 + (size_t)(t - 25) * 524288);
  #pragma unroll
  for (int i = 0; i < 32; ++i) gxs[(size_t)(r0 + i) * 1024 + b] = acc[i];
}

// ---------------- fused encoder + decoder + output head (cooperative) ----------------
// 256 blocks x 256 threads: bx = batch quarter (blockIdx.x & 3), by = r-group
// (blockIdx.x >> 2, 8 gate-rows = 2 units each). Weight slices cached in LDS once.
// Output head (12 outputs) folded into dec k-loop for by < 12 (reuses hv loads).
__global__ __launch_bounds__(256) void k_seq(
    const float* __restrict__ gx0, const float* __restrict__ gx1,
    const float* __restrict__ WENC, const float* __restrict__ WDEC,
    const float* __restrict__ bdec,
    float* __restrict__ hA, float* __restrict__ hB, float* __restrict__ cbuf,
    const float* __restrict__ ow, const float* __restrict__ ob,
    float* __restrict__ out) {
  cg::grid_group grid = cg::this_grid();
  const int bx = blockIdx.x & 3;
  const int by = blockIdx.x >> 2;       // 0..63
  const int r0 = by * 8;
  const int b  = bx * 256 + (int)threadIdx.x;
  const int u0 = r0 >> 2;               // first of 2 units

  __shared__ float wenc[1024];          // [k][8] enc h-part slice
  __shared__ float wdec[1024];          // [k][8] dec slice
  __shared__ float owl[128];            // out_w row (by < 12)

  for (int idx = threadIdx.x; idx < 1024; idx += 256) {
    int k = idx >> 3, i = idx & 7;
    wenc[idx] = WENC[(64 + k) * 512 + r0 + i];
    wdec[idx] = WDEC[k * 512 + r0 + i];
  }
  if (by < 12)
    for (int k = threadIdx.x; k < 128; k += 256) owl[k] = ow[by * 128 + k];
  __syncthreads();

  float bd[8];
  #pragma unroll
  for (int i = 0; i < 8; ++i) bd[i] = bdec[r0 + i];
  const float obv = (by < 12) ? ob[by] : 0.f;

  float* hp = hA;
  float* hn = hB;

  // ---- encoder: 32 steps (x-part precomputed in gx) ----
  for (int t = 0; t < TSEQ; ++t) {
    const float* gxs = (t < 25) ? (gx0 + (size_t)t * 524288)
                                : (gx1 + (size_t)(t - 25) * 524288);
    float acc[8];
    #pragma unroll
    for (int i = 0; i < 8; ++i) acc[i] = gxs[(size_t)(r0 + i) * 1024 + b];
    #pragma unroll 4
    for (int k = 0; k < 128; ++k) {
      float hv = hp[k * 1024 + b];
      float4 w0 = *(const float4*)&wenc[k * 8];
      float4 w1 = *(const float4*)&wenc[k * 8 + 4];
      acc[0] = fmaf(w0.x, hv, acc[0]);
      acc[1] = fmaf(w0.y, hv, acc[1]);
      acc[2] = fmaf(w0.z, hv, acc[2]);
      acc[3] = fmaf(w0.w, hv, acc[3]);
      acc[4] = fmaf(w1.x, hv, acc[4]);
      acc[5] = fmaf(w1.y, hv, acc[5]);
      acc[6] = fmaf(w1.z, hv, acc[6]);
      acc[7] = fmaf(w1.w, hv, acc[7]);
    }
    #pragma unroll
    for (int uu = 0; uu < 2; ++uu) {
      int u = u0 + uu;
      float cn = sigf(acc[uu * 4 + 1]) * cbuf[u * 1024 + b]
               + sigf(acc[uu * 4 + 0]) * tanhfast(acc[uu * 4 + 2]);
      float hv2 = sigf(acc[uu * 4 + 3]) * tanhfast(cn);
      cbuf[u * 1024 + b] = cn;
      hn[u * 1024 + b] = hv2;
    }
    float* tmp = hp; hp = hn; hn = tmp;
    __threadfence();
    grid.sync();
  }

  // ---- decoder: 10 steps (x_in == h => W = W_ih + W_hh); out head for t-1 fused ----
  for (int t = 0; t < 10; ++t) {
    float acc[8];
    #pragma unroll
    for (int i = 0; i < 8; ++i) acc[i] = bd[i];
    float oacc = obv;
    #pragma unroll 4
    for (int k = 0; k < 128; ++k) {
      float hv = hp[k * 1024 + b];
      float4 w0 = *(const float4*)&wdec[k * 8];
      float4 w1 = *(const float4*)&wdec[k * 8 + 4];
      acc[0] = fmaf(w0.x, hv, acc[0]);
      acc[1] = fmaf(w0.y, hv, acc[1]);
      acc[2] = fmaf(w0.z, hv, acc[2]);
      acc[3] = fmaf(w0.w, hv, acc[3]);
      acc[4] = fmaf(w1.x, hv, acc[4]);
      acc[5] = fmaf(w1.y, hv, acc[5]);
      acc[6] = fmaf(w1.z, hv, acc[6]);
      acc[7] = fmaf(w1.w, hv, acc[7]);
      if (by < 12) oacc = fmaf(owl[k], hv, oacc);
    }
    if (t > 0 && by < 12) out[b * 120 + (t - 1) * 12 + by] = oacc;
    #pragma unroll
    for (int uu = 0; uu < 2; ++uu) {
      int u = u0 + uu;
      float cn = sigf(acc[uu * 4 + 1]) * cbuf[u * 1024 + b]
               + sigf(acc[uu * 4 + 0]) * tanhfast(acc[uu * 4 + 2]);
      float hv2 = sigf(acc[uu * 4 + 3]) * tanhfast(cn);
      cbuf[u * 1024 + b] = cn;
      hn[u * 1024 + b] = hv2;
    }
    float* tmp = hp; hp = hn; hn = tmp;
    __threadfence();
    grid.sync();
  }

  // ---- out head for final step (t = 9) from final h ----
  if (by < 12) {
    float oacc = obv;
    for (int k = 0; k < 128; ++k)
      oacc = fmaf(owl[k], hp[k * 1024 + b], oacc);
    out[b * 120 + 108 + by] = oacc;
  }
}

// ---------------- launch ----------------
extern "C" void kernel_launch(void* const* d_in, const int* in_sizes, int n_in,
                              void* d_out, int out_size, void* d_ws, size_t ws_size,
                              hipStream_t stream) {
  const float* obs  = (const float*)d_in[0];
  const float* c1w  = (const float*)d_in[1];
  const float* c1b  = (const float*)d_in[2];
  const float* c2w  = (const float*)d_in[3];
  const float* c2b  = (const float*)d_in[4];
  const float* f1w  = (const float*)d_in[5];
  const float* f1b  = (const float*)d_in[6];
  const float* g1   = (const float*)d_in[7];
  const float* be1  = (const float*)d_in[8];
  const float* m1   = (const float*)d_in[9];
  const float* v1   = (const float*)d_in[10];
  const float* f2w  = (const float*)d_in[11];
  const float* f2b  = (const float*)d_in[12];
  const float* g2   = (const float*)d_in[13];
  const float* be2  = (const float*)d_in[14];
  const float* m2   = (const float*)d_in[15];
  const float* v2   = (const float*)d_in[16];
  const float* ewih = (const float*)d_in[17];
  const float* ewhh = (const float*)d_in[18];
  const float* eb   = (const float*)d_in[19];
  const float* dwih = (const float*)d_in[20];
  const float* dwhh = (const float*)d_in[21];
  const float* db   = (const float*)d_in[22];
  const float* ow   = (const float*)d_in[23];
  const float* ob   = (const float*)d_in[24];
  float* ws  = (float*)d_ws;
  float* out = (float*)d_out;

  // weight prep + state zeroing
  k_setup<<<2297, 256, 0, stream>>>(c1w, c2w, f1w, f1b, g1, be1, m1, v1,
                                    f2w, f2b, g2, be2, m2, v2,
                                    ewih, ewhh, eb, dwih, dwhh, db, ws);
  // obs -> frame-last layout
  k_transpose<<<dim3(200, 16), 256, 0, stream>>>(obs, ws + OBS_T);
  // CNN
  k_conv1<<<dim3(128, 25), 256, 0, stream>>>(ws + OBS_T, ws + W_C1, c1b, ws + POOL1);
  k_conv2<<<dim3(128, 8), 256, 0, stream>>>(ws + POOL1, ws + W_C2, c2b, ws + POOL2);
  // FC1 + BN + relu ; FC2 + BN + relu
  k_fc16<<<dim3(128, 8), 256, 0, stream>>>(ws + POOL2, ws + W_F1, ws + B_F1, ws + Y1, 128, 128);
  k_fc16<<<dim3(128, 4), 256, 0, stream>>>(ws + Y1, ws + W_F2, ws + B_F2, ws + FEATS, 128, 64);
  // encoder x-projection for all 32 timesteps (parallel)
  k_xgates<<<dim3(128, 16), 256, 0, stream>>>(ws + FEATS, ws + W_ENC, ws + B_ENC,
                                              ws + GX0, ws + GX1);
  // fused encoder+decoder+head: one cooperative launch, grid.sync between steps
  {
    float* gx0p  = ws + GX0;
    float* gx1p  = ws + GX1;
    float* wencp = ws + W_ENC;
    float* wdecp = ws + W_DEC;
    float* bdecp = ws + B_DEC;
    float* hAp   = ws + HA;
    float* hBp   = ws + HB;
    float* cbp   = ws + CC;
    void* args[] = { &gx0p, &gx1p, &wencp, &wdecp, &bdecp,
                     &hAp, &hBp, &cbp, (void*)&ow, (void*)&ob, &out };
    hipLaunchCooperativeKernel((void*)k_seq, dim3(256), dim3(256), args, 0, stream);
  }
}

// Round 4
// 678.161 us; speedup vs baseline: 4.9611x; 4.9611x over previous
//
#include <hip/hip_runtime.h>
#include <hip/hip_bf16.h>

// ---------------- problem constants ----------------
constexpr int GT = 32768;          // B*T frames
constexpr int TSEQ = 32;

// ---------------- workspace layout (floats) ----------------
// R0 [0, 13107200): obsT [400][GT]; reused: pool2 [128][GT]@0, y1 [128][GT]@4194304;
//                   after fc2 reused: gates_x slices t=0..24 (25 x 524288)
// R1 [13107200, 26214400): pool1 [400][GT]; reused: featsT [64][GT]@13107200,
//                   gates_x slices t=25..31 @ 15204352
constexpr size_t OBS_T = 0;
constexpr size_t POOL1 = 13107200;
constexpr size_t POOL2 = 0;
constexpr size_t Y1    = 4194304;
constexpr size_t FEATS = 13107200;
constexpr size_t GX0   = 0;                 // t<25, layout [t][b][512]
constexpr size_t GX1   = 15204352;          // t>=25
constexpr size_t WB    = 26214400;          // weights region
constexpr size_t W_C1  = WB + 0;            // 576   : conv1 wT [36][16]
constexpr size_t W_C2  = WB + 576;          // 4608  : conv2 wT [144][32]
constexpr size_t W_F1  = WB + 5184;         // 16384 : fc1 wT [128][128], BN folded
constexpr size_t B_F1  = WB + 21568;        // 128
constexpr size_t W_F2  = WB + 21696;        // 8192  : fc2 wT [128][64], BN folded
constexpr size_t B_F2  = WB + 29888;        // 64
constexpr size_t W_ENC = WB + 29952;        // 98304 : enc wT [192][512], rows r=u*4+gate
constexpr size_t B_ENC = WB + 128256;       // 512
constexpr size_t W_DEC = WB + 128768;       // 65536 : (dec_w_ih+dec_w_hh) wT [128][512]
constexpr size_t B_DEC = WB + 194304;       // 512

__device__ __forceinline__ float sigf(float x)  { return 1.f / (1.f + __expf(-x)); }
__device__ __forceinline__ float tanhfast(float x) { return 1.f - 2.f / (__expf(2.f * x) + 1.f); }

// ---------------- setup: transpose/fold weights (no state zeroing needed) ----------
__global__ __launch_bounds__(256) void k_setup(
    const float* __restrict__ c1w, const float* __restrict__ c2w,
    const float* __restrict__ f1w, const float* __restrict__ f1b,
    const float* __restrict__ g1, const float* __restrict__ be1,
    const float* __restrict__ m1, const float* __restrict__ v1,
    const float* __restrict__ f2w, const float* __restrict__ f2b,
    const float* __restrict__ g2, const float* __restrict__ be2,
    const float* __restrict__ m2, const float* __restrict__ v2,
    const float* __restrict__ ewih, const float* __restrict__ ewhh, const float* __restrict__ eb,
    const float* __restrict__ dwih, const float* __restrict__ dwhh, const float* __restrict__ db,
    float* __restrict__ ws) {
  long i = (long)blockIdx.x * 256 + threadIdx.x;
  if (i < 576)  { int c = i & 15, r = i >> 4; ws[W_C1 + i] = c1w[c * 36 + r]; return; }
  i -= 576;
  if (i < 4608) { int c = i & 31, r = i >> 5; ws[W_C2 + i] = c2w[c * 144 + r]; return; }
  i -= 4608;
  if (i < 16384) { int j = i & 127, k = i >> 7;
    float s = g1[j] * rsqrtf(v1[j] + 1e-5f);
    ws[W_F1 + i] = f1w[j * 128 + k] * s; return; }
  i -= 16384;
  if (i < 128) { int j = i; float s = g1[j] * rsqrtf(v1[j] + 1e-5f);
    ws[B_F1 + i] = (f1b[j] - m1[j]) * s + be1[j]; return; }
  i -= 128;
  if (i < 8192) { int j = i & 63, k = i >> 6;
    float s = g2[j] * rsqrtf(v2[j] + 1e-5f);
    ws[W_F2 + i] = f2w[j * 128 + k] * s; return; }
  i -= 8192;
  if (i < 64) { int j = i; float s = g2[j] * rsqrtf(v2[j] + 1e-5f);
    ws[B_F2 + i] = (f2b[j] - m2[j]) * s + be2[j]; return; }
  i -= 64;
  if (i < 98304) { int r = i & 511, k = i >> 9;
    int u = r >> 2, gt = r & 3, jr = gt * 128 + u;
    ws[W_ENC + i] = (k < 64) ? ewih[jr * 64 + k] : ewhh[jr * 128 + (k - 64)]; return; }
  i -= 98304;
  if (i < 512) { int u = i >> 2, gt = i & 3; ws[B_ENC + i] = eb[gt * 128 + u]; return; }
  i -= 512;
  if (i < 65536) { int r = i & 511, k = i >> 9;
    int u = r >> 2, gt = r & 3, jr = gt * 128 + u;
    ws[W_DEC + i] = dwih[jr * 128 + k] + dwhh[jr * 128 + k]; return; }
  i -= 65536;
  if (i < 512) { int u = i >> 2, gt = i & 3; ws[B_DEC + i] = db[gt * 128 + u]; return; }
}

// ---------------- transpose obs [b][tp] -> obsT [p][t][b], float4 loads ----------------
__global__ __launch_bounds__(256) void k_transpose(const float* __restrict__ obs,
                                                   float* __restrict__ obsT) {
  __shared__ float tile[64][65];
  int tp0 = blockIdx.x * 64;        // 200 tiles over tp=12800
  int b0  = blockIdx.y * 64;        // 16 tiles over b=1024
  int q     = threadIdx.x & 15;
  int rbase = threadIdx.x >> 4;
  #pragma unroll
  for (int rr = 0; rr < 4; ++rr) {
    int row = rbase + rr * 16;
    const float4 v = *(const float4*)(obs + (size_t)(b0 + row) * 12800 + tp0 + q * 4);
    tile[row][q * 4 + 0] = v.x;
    tile[row][q * 4 + 1] = v.y;
    tile[row][q * 4 + 2] = v.z;
    tile[row][q * 4 + 3] = v.w;
  }
  __syncthreads();
  int lane = threadIdx.x & 63;
  int grp  = threadIdx.x >> 6;
  for (int cc = 0; cc < 16; ++cc) {
    int col = grp * 16 + cc;
    int tp = tp0 + col;
    int t = tp / 400, p = tp % 400;
    obsT[(size_t)p * GT + t * 1024 + b0 + lane] = tile[lane][col];
  }
}

// ---------------- conv1 (4->16, 3x3 SAME on 10x10) + relu + maxpool2 ----------------
__global__ __launch_bounds__(256) void k_conv1(const float* __restrict__ obsT,
                                               const float* __restrict__ wT,
                                               const float* __restrict__ bias,
                                               float* __restrict__ pool1) {
  int g = blockIdx.x * 256 + threadIdx.x;
  int pos = blockIdx.y;
  int py = pos / 5, px = pos % 5;
  float acc[4][16];
  #pragma unroll
  for (int s = 0; s < 4; ++s)
    #pragma unroll
    for (int c = 0; c < 16; ++c) acc[s][c] = 0.f;

  #pragma unroll 1
  for (int ci = 0; ci < 4; ++ci) {
    float p[16];
    #pragma unroll
    for (int r = 0; r < 4; ++r) {
      int iy = 2 * py + r - 1;
      #pragma unroll
      for (int cx = 0; cx < 4; ++cx) {
        int ix = 2 * px + cx - 1;
        bool ok = ((unsigned)iy < 10u) && ((unsigned)ix < 10u);   // wave-uniform
        p[r * 4 + cx] = ok ? obsT[(size_t)(ci * 100 + iy * 10 + ix) * GT + g] : 0.f;
      }
    }
    #pragma unroll
    for (int t9 = 0; t9 < 9; ++t9) {
      int ky = t9 / 3, kx = t9 % 3;
      const float* w = wT + ((ci * 9 + t9) << 4);
      float wv[16];
      #pragma unroll
      for (int c = 0; c < 16; ++c) wv[c] = w[c];
      #pragma unroll
      for (int dy = 0; dy < 2; ++dy)
        #pragma unroll
        for (int dx = 0; dx < 2; ++dx) {
          float xv = p[(dy + ky) * 4 + (dx + kx)];
          #pragma unroll
          for (int c = 0; c < 16; ++c)
            acc[dy * 2 + dx][c] = fmaf(wv[c], xv, acc[dy * 2 + dx][c]);
        }
    }
  }
  #pragma unroll
  for (int c = 0; c < 16; ++c) {
    float m = fmaxf(fmaxf(acc[0][c], acc[1][c]), fmaxf(acc[2][c], acc[3][c]));
    m = fmaxf(m + bias[c], 0.f);
    pool1[(size_t)(c * 25 + pos) * GT + g] = m;
  }
}

// ---------------- conv2 (16->32, 3x3 SAME on 5x5) + relu + maxpool2(floor) ----------------
__global__ __launch_bounds__(256) void k_conv2(const float* __restrict__ pool1,
                                               const float* __restrict__ wT,
                                               const float* __restrict__ bias,
                                               float* __restrict__ pool2) {
  int g = blockIdx.x * 256 + threadIdx.x;
  int pos = blockIdx.y & 3;
  int h = blockIdx.y >> 2;
  int py = pos >> 1, px = pos & 1;
  float acc[4][16];
  #pragma unroll
  for (int s = 0; s < 4; ++s)
    #pragma unroll
    for (int c = 0; c < 16; ++c) acc[s][c] = 0.f;

  #pragma unroll 1
  for (int ci = 0; ci < 16; ++ci) {
    float p[16];
    #pragma unroll
    for (int r = 0; r < 4; ++r) {
      int iy = 2 * py + r - 1;
      #pragma unroll
      for (int cx = 0; cx < 4; ++cx) {
        int ix = 2 * px + cx - 1;
        bool ok = ((unsigned)iy < 5u) && ((unsigned)ix < 5u);     // wave-uniform
        p[r * 4 + cx] = ok ? pool1[(size_t)(ci * 25 + iy * 5 + ix) * GT + g] : 0.f;
      }
    }
    #pragma unroll
    for (int t9 = 0; t9 < 9; ++t9) {
      int ky = t9 / 3, kx = t9 % 3;
      const float* w = wT + (ci * 9 + t9) * 32 + h * 16;
      float wv[16];
      #pragma unroll
      for (int c = 0; c < 16; ++c) wv[c] = w[c];
      #pragma unroll
      for (int dy = 0; dy < 2; ++dy)
        #pragma unroll
        for (int dx = 0; dx < 2; ++dx) {
          float xv = p[(dy + ky) * 4 + (dx + kx)];
          #pragma unroll
          for (int c = 0; c < 16; ++c)
            acc[dy * 2 + dx][c] = fmaf(wv[c], xv, acc[dy * 2 + dx][c]);
        }
    }
  }
  #pragma unroll
  for (int c = 0; c < 16; ++c) {
    float m = fmaxf(fmaxf(acc[0][c], acc[1][c]), fmaxf(acc[2][c], acc[3][c]));
    m = fmaxf(m + bias[h * 16 + c], 0.f);
    int cp2 = (h * 16 + c) * 4 + pos;
    pool2[(size_t)cp2 * GT + g] = m;
  }
}

// ---------------- FC (+folded BN) + relu, 16 outputs/thread ----------------
__global__ __launch_bounds__(256) void k_fc16(const float* __restrict__ x,
                                              const float* __restrict__ WT,
                                              const float* __restrict__ bf,
                                              float* __restrict__ y, int K, int J) {
  int g = blockIdx.x * 256 + threadIdx.x;
  int j0 = blockIdx.y * 16;
  float acc[16];
  #pragma unroll
  for (int c = 0; c < 16; ++c) acc[c] = 0.f;
  for (int k = 0; k < K; ++k) {
    float xv = x[(size_t)k * GT + g];
    const float* w = WT + (size_t)k * J + j0;
    #pragma unroll
    for (int c = 0; c < 16; ++c) acc[c] = fmaf(w[c], xv, acc[c]);
  }
  #pragma unroll
  for (int c = 0; c < 16; ++c)
    y[(size_t)(j0 + c) * GT + g] = fmaxf(acc[c] + bf[j0 + c], 0.f);
}

// ---------------- encoder x-projection for ALL timesteps (parallel, bias folded) ----
// NEW layout: gx[t][b][512] so k_seq2's per-(b,r0) reads are two coalesced float4s.
__global__ __launch_bounds__(256) void k_xgates(const float* __restrict__ feats,
                                                const float* __restrict__ WT,
                                                const float* __restrict__ br,
                                                float* __restrict__ gx0,
                                                float* __restrict__ gx1) {
  int t  = blockIdx.x >> 2;
  int bq = blockIdx.x & 3;
  int b  = bq * 256 + threadIdx.x;
  int r0 = blockIdx.y * 32;
  float acc[32];
  #pragma unroll
  for (int i = 0; i < 32; ++i) acc[i] = br[r0 + i];
  const float* xcol = feats + (size_t)t * 1024 + b;
  for (int k = 0; k < 64; ++k) {
    float xv = xcol[(size_t)k * GT];
    const float* w = WT + k * 512 + r0;
    #pragma unroll
    for (int i = 0; i < 32; ++i) acc[i] = fmaf(w[i], xv, acc[i]);
  }
  float* gxs = (t < 25) ? (gx0 + (size_t)t * 524288)
                        : (gx1 + (size_t)(t - 25) * 524288);
  #pragma unroll
  for (int i = 0; i < 32; ++i) gxs[(size_t)b * 512 + r0 + i] = acc[i];
}

// ---------------- fused enc+dec+head, batch-partitioned: NO cross-block sync ----------
// 256 blocks x 256 threads. Block owns 4 batch elems; computes ALL 512 gate rows.
// thread: bl = tid&3 (batch), g = tid>>2 (0..63; 8 gate rows = 2 units).
// h double-buffered in LDS (stride 132 kills bank conflicts); c stays in registers.
// Weights stream from L2 every step (256 KB/CU/step; resident in each XCD L2).
constexpr int HS = 132;   // padded h row stride (132 % 32 = 4 -> per-b bank offset)
__global__ __launch_bounds__(256) void k_seq2(
    const float* __restrict__ gx0, const float* __restrict__ gx1,
    const float* __restrict__ WENC, const float* __restrict__ WDEC,
    const float* __restrict__ bdec,
    const float* __restrict__ ow, const float* __restrict__ ob,
    float* __restrict__ out) {
  const int tid = threadIdx.x;
  const int bl  = tid & 3;
  const int g   = tid >> 2;           // 0..63
  const int r0  = g * 8;
  const int u0  = g * 2;
  const int b   = blockIdx.x * 4 + bl;

  __shared__ float hbuf[2][4 * HS];   // [buf][bl*HS + k]
  __shared__ float owl[12 * HS];      // padded out_w rows

  for (int i = tid; i < 4 * HS; i += 256) { hbuf[0][i] = 0.f; }
  for (int i = tid; i < 1536; i += 256) owl[(i >> 7) * HS + (i & 127)] = ow[i];

  float c0 = 0.f, c1 = 0.f;
  float bd[8];
  #pragma unroll
  for (int i = 0; i < 8; ++i) bd[i] = bdec[r0 + i];
  __syncthreads();

  int cur = 0;

  // ---- encoder: 32 steps; x-part precomputed in gx[t][b][512] ----
  for (int t = 0; t < TSEQ; ++t) {
    const float* gxs = (t < 25) ? (gx0 + (size_t)t * 524288)
                                : (gx1 + (size_t)(t - 25) * 524288);
    const float* gb = gxs + (size_t)b * 512 + r0;
    float4 a0 = *(const float4*)gb;
    float4 a1 = *(const float4*)(gb + 4);
    float acc[8] = {a0.x, a0.y, a0.z, a0.w, a1.x, a1.y, a1.z, a1.w};
    const float* hc = &hbuf[cur][bl * HS];
    #pragma unroll 2
    for (int k4 = 0; k4 < 32; ++k4) {
      float4 hv4 = *(const float4*)&hc[k4 * 4];
      const float* wb = WENC + (size_t)(64 + k4 * 4) * 512 + r0;
      #pragma unroll
      for (int j = 0; j < 4; ++j) {
        float hv = (&hv4.x)[j];
        float4 w0 = *(const float4*)(wb + j * 512);
        float4 w1 = *(const float4*)(wb + j * 512 + 4);
        acc[0] = fmaf(w0.x, hv, acc[0]);
        acc[1] = fmaf(w0.y, hv, acc[1]);
        acc[2] = fmaf(w0.z, hv, acc[2]);
        acc[3] = fmaf(w0.w, hv, acc[3]);
        acc[4] = fmaf(w1.x, hv, acc[4]);
        acc[5] = fmaf(w1.y, hv, acc[5]);
        acc[6] = fmaf(w1.z, hv, acc[6]);
        acc[7] = fmaf(w1.w, hv, acc[7]);
      }
    }
    float cn0 = sigf(acc[1]) * c0 + sigf(acc[0]) * tanhfast(acc[2]);
    float cn1 = sigf(acc[5]) * c1 + sigf(acc[4]) * tanhfast(acc[6]);
    c0 = cn0; c1 = cn1;
    float hn0 = sigf(acc[3]) * tanhfast(cn0);
    float hn1 = sigf(acc[7]) * tanhfast(cn1);
    __syncthreads();                          // everyone done reading hbuf[cur]
    *(float2*)&hbuf[cur ^ 1][bl * HS + u0] = make_float2(hn0, hn1);
    __syncthreads();                          // hbuf[nxt] complete
    cur ^= 1;
  }

  // ---- decoder: 10 steps (x_in == h => W = W_ih + W_hh); head fused ----
  for (int t = 0; t < 10; ++t) {
    float acc[8];
    #pragma unroll
    for (int i = 0; i < 8; ++i) acc[i] = bd[i];
    const float* hc = &hbuf[cur][bl * HS];
    #pragma unroll 2
    for (int k4 = 0; k4 < 32; ++k4) {
      float4 hv4 = *(const float4*)&hc[k4 * 4];
      const float* wb = WDEC + (size_t)(k4 * 4) * 512 + r0;
      #pragma unroll
      for (int j = 0; j < 4; ++j) {
        float hv = (&hv4.x)[j];
        float4 w0 = *(const float4*)(wb + j * 512);
        float4 w1 = *(const float4*)(wb + j * 512 + 4);
        acc[0] = fmaf(w0.x, hv, acc[0]);
        acc[1] = fmaf(w0.y, hv, acc[1]);
        acc[2] = fmaf(w0.z, hv, acc[2]);
        acc[3] = fmaf(w0.w, hv, acc[3]);
        acc[4] = fmaf(w1.x, hv, acc[4]);
        acc[5] = fmaf(w1.y, hv, acc[5]);
        acc[6] = fmaf(w1.z, hv, acc[6]);
        acc[7] = fmaf(w1.w, hv, acc[7]);
      }
    }
    float cn0 = sigf(acc[1]) * c0 + sigf(acc[0]) * tanhfast(acc[2]);
    float cn1 = sigf(acc[5]) * c1 + sigf(acc[4]) * tanhfast(acc[6]);
    c0 = cn0; c1 = cn1;
    float hn0 = sigf(acc[3]) * tanhfast(cn0);
    float hn1 = sigf(acc[7]) * tanhfast(cn1);
    __syncthreads();
    *(float2*)&hbuf[cur ^ 1][bl * HS + u0] = make_float2(hn0, hn1);
    __syncthreads();
    cur ^= 1;
    // output head for this step's new h (tid<48: bl x o), reads LDS only
    if (tid < 48) {
      int o = tid >> 2;
      const float* hh = &hbuf[cur][bl * HS];
      const float* wo = &owl[o * HS];
      float oacc = ob[o];
      #pragma unroll 4
      for (int k = 0; k < 128; ++k) oacc = fmaf(wo[k], hh[k], oacc);
      out[b * 120 + t * 12 + o] = oacc;
    }
    // no extra sync needed: next step writes hbuf[cur^1], head reads hbuf[cur];
    // the end-of-step barrier orders head vs any later overwrite of this buffer.
  }
}

// ---------------- launch ----------------
extern "C" void kernel_launch(void* const* d_in, const int* in_sizes, int n_in,
                              void* d_out, int out_size, void* d_ws, size_t ws_size,
                              hipStream_t stream) {
  const float* obs  = (const float*)d_in[0];
  const float* c1w  = (const float*)d_in[1];
  const float* c1b  = (const float*)d_in[2];
  const float* c2w  = (const float*)d_in[3];
  const float* c2b  = (const float*)d_in[4];
  const float* f1w  = (const float*)d_in[5];
  const float* f1b  = (const float*)d_in[6];
  const float* g1   = (const float*)d_in[7];
  const float* be1  = (const float*)d_in[8];
  const float* m1   = (const float*)d_in[9];
  const float* v1   = (const float*)d_in[10];
  const float* f2w  = (const float*)d_in[11];
  const float* f2b  = (const float*)d_in[12];
  const float* g2   = (const float*)d_in[13];
  const float* be2  = (const float*)d_in[14];
  const float* m2   = (const float*)d_in[15];
  const float* v2   = (const float*)d_in[16];
  const float* ewih = (const float*)d_in[17];
  const float* ewhh = (const float*)d_in[18];
  const float* eb   = (const float*)d_in[19];
  const float* dwih = (const float*)d_in[20];
  const float* dwhh = (const float*)d_in[21];
  const float* db   = (const float*)d_in[22];
  const float* ow   = (const float*)d_in[23];
  const float* ob   = (const float*)d_in[24];
  float* ws  = (float*)d_ws;
  float* out = (float*)d_out;

  // weight prep (194816 items = 761 blocks x 256)
  k_setup<<<761, 256, 0, stream>>>(c1w, c2w, f1w, f1b, g1, be1, m1, v1,
                                   f2w, f2b, g2, be2, m2, v2,
                                   ewih, ewhh, eb, dwih, dwhh, db, ws);
  // obs -> frame-last layout
  k_transpose<<<dim3(200, 16), 256, 0, stream>>>(obs, ws + OBS_T);
  // CNN
  k_conv1<<<dim3(128, 25), 256, 0, stream>>>(ws + OBS_T, ws + W_C1, c1b, ws + POOL1);
  k_conv2<<<dim3(128, 8), 256, 0, stream>>>(ws + POOL1, ws + W_C2, c2b, ws + POOL2);
  // FC1 + BN + relu ; FC2 + BN + relu
  k_fc16<<<dim3(128, 8), 256, 0, stream>>>(ws + POOL2, ws + W_F1, ws + B_F1, ws + Y1, 128, 128);
  k_fc16<<<dim3(128, 4), 256, 0, stream>>>(ws + Y1, ws + W_F2, ws + B_F2, ws + FEATS, 128, 64);
  // encoder x-projection for all 32 timesteps (parallel)
  k_xgates<<<dim3(128, 16), 256, 0, stream>>>(ws + FEATS, ws + W_ENC, ws + B_ENC,
                                              ws + GX0, ws + GX1);
  // fused encoder + decoder + output head: ONE normal launch, LDS-only recurrence
  k_seq2<<<256, 256, 0, stream>>>(ws + GX0, ws + GX1, ws + W_ENC, ws + W_DEC,
                                  ws + B_DEC, ow, ob, out);
}

// Round 5
// 585.786 us; speedup vs baseline: 5.7435x; 1.1577x over previous
//
#include <hip/hip_runtime.h>
#include <hip/hip_bf16.h>

// ---------------- problem constants ----------------
constexpr int GT = 32768;          // B*T frames
constexpr int TSEQ = 32;

// ---------------- workspace layout (floats) ----------------
constexpr size_t OBS_T = 0;
constexpr size_t POOL1 = 13107200;
constexpr size_t POOL2 = 0;
constexpr size_t Y1    = 4194304;
constexpr size_t FEATS = 13107200;
constexpr size_t GX0   = 0;                 // t<25, layout [t][b][512]
constexpr size_t GX1   = 15204352;          // t>=25
constexpr size_t WB    = 26214400;          // weights region
constexpr size_t W_C1  = WB + 0;            // 576   : conv1 wT [36][16]
constexpr size_t W_C2  = WB + 576;          // 4608  : conv2 wT [144][32]
constexpr size_t W_F1  = WB + 5184;         // 16384 : fc1 wT [128][128], BN folded
constexpr size_t B_F1  = WB + 21568;        // 128
constexpr size_t W_F2  = WB + 21696;        // 8192  : fc2 wT [128][64], BN folded
constexpr size_t B_F2  = WB + 29888;        // 64
constexpr size_t W_ENC = WB + 29952;        // 98304 : enc wT [192][512], rows r=u*4+gate
constexpr size_t B_ENC = WB + 128256;       // 512
constexpr size_t W_DEC = WB + 128768;       // 65536 : (dec_w_ih+dec_w_hh) wT [128][512]
constexpr size_t B_DEC = WB + 194304;       // 512

__device__ __forceinline__ float sigf(float x)  { return 1.f / (1.f + __expf(-x)); }
__device__ __forceinline__ float tanhfast(float x) { return 1.f - 2.f / (__expf(2.f * x) + 1.f); }

// ---------------- setup: transpose/fold weights ----------
__global__ __launch_bounds__(256) void k_setup(
    const float* __restrict__ c1w, const float* __restrict__ c2w,
    const float* __restrict__ f1w, const float* __restrict__ f1b,
    const float* __restrict__ g1, const float* __restrict__ be1,
    const float* __restrict__ m1, const float* __restrict__ v1,
    const float* __restrict__ f2w, const float* __restrict__ f2b,
    const float* __restrict__ g2, const float* __restrict__ be2,
    const float* __restrict__ m2, const float* __restrict__ v2,
    const float* __restrict__ ewih, const float* __restrict__ ewhh, const float* __restrict__ eb,
    const float* __restrict__ dwih, const float* __restrict__ dwhh, const float* __restrict__ db,
    float* __restrict__ ws) {
  long i = (long)blockIdx.x * 256 + threadIdx.x;
  if (i < 576)  { int c = i & 15, r = i >> 4; ws[W_C1 + i] = c1w[c * 36 + r]; return; }
  i -= 576;
  if (i < 4608) { int c = i & 31, r = i >> 5; ws[W_C2 + i] = c2w[c * 144 + r]; return; }
  i -= 4608;
  if (i < 16384) { int j = i & 127, k = i >> 7;
    float s = g1[j] * rsqrtf(v1[j] + 1e-5f);
    ws[W_F1 + i] = f1w[j * 128 + k] * s; return; }
  i -= 16384;
  if (i < 128) { int j = i; float s = g1[j] * rsqrtf(v1[j] + 1e-5f);
    ws[B_F1 + i] = (f1b[j] - m1[j]) * s + be1[j]; return; }
  i -= 128;
  if (i < 8192) { int j = i & 63, k = i >> 6;
    float s = g2[j] * rsqrtf(v2[j] + 1e-5f);
    ws[W_F2 + i] = f2w[j * 128 + k] * s; return; }
  i -= 8192;
  if (i < 64) { int j = i; float s = g2[j] * rsqrtf(v2[j] + 1e-5f);
    ws[B_F2 + i] = (f2b[j] - m2[j]) * s + be2[j]; return; }
  i -= 64;
  if (i < 98304) { int r = i & 511, k = i >> 9;
    int u = r >> 2, gt = r & 3, jr = gt * 128 + u;
    ws[W_ENC + i] = (k < 64) ? ewih[jr * 64 + k] : ewhh[jr * 128 + (k - 64)]; return; }
  i -= 98304;
  if (i < 512) { int u = i >> 2, gt = i & 3; ws[B_ENC + i] = eb[gt * 128 + u]; return; }
  i -= 512;
  if (i < 65536) { int r = i & 511, k = i >> 9;
    int u = r >> 2, gt = r & 3, jr = gt * 128 + u;
    ws[W_DEC + i] = dwih[jr * 128 + k] + dwhh[jr * 128 + k]; return; }
  i -= 65536;
  if (i < 512) { int u = i >> 2, gt = i & 3; ws[B_DEC + i] = db[gt * 128 + u]; return; }
}

// ---------------- transpose obs [b][tp] -> obsT [p][t][b], float4 loads ----------------
__global__ __launch_bounds__(256) void k_transpose(const float* __restrict__ obs,
                                                   float* __restrict__ obsT) {
  __shared__ float tile[64][65];
  int tp0 = blockIdx.x * 64;
  int b0  = blockIdx.y * 64;
  int q     = threadIdx.x & 15;
  int rbase = threadIdx.x >> 4;
  #pragma unroll
  for (int rr = 0; rr < 4; ++rr) {
    int row = rbase + rr * 16;
    const float4 v = *(const float4*)(obs + (size_t)(b0 + row) * 12800 + tp0 + q * 4);
    tile[row][q * 4 + 0] = v.x;
    tile[row][q * 4 + 1] = v.y;
    tile[row][q * 4 + 2] = v.z;
    tile[row][q * 4 + 3] = v.w;
  }
  __syncthreads();
  int lane = threadIdx.x & 63;
  int grp  = threadIdx.x >> 6;
  for (int cc = 0; cc < 16; ++cc) {
    int col = grp * 16 + cc;
    int tp = tp0 + col;
    int t = tp / 400, p = tp % 400;
    obsT[(size_t)p * GT + t * 1024 + b0 + lane] = tile[lane][col];
  }
}

// ---------------- conv1 (4->16, 3x3 SAME on 10x10) + relu + maxpool2 ----------------
__global__ __launch_bounds__(256) void k_conv1(const float* __restrict__ obsT,
                                               const float* __restrict__ wT,
                                               const float* __restrict__ bias,
                                               float* __restrict__ pool1) {
  int g = blockIdx.x * 256 + threadIdx.x;
  int pos = blockIdx.y;
  int py = pos / 5, px = pos % 5;
  float acc[4][16];
  #pragma unroll
  for (int s = 0; s < 4; ++s)
    #pragma unroll
    for (int c = 0; c < 16; ++c) acc[s][c] = 0.f;

  #pragma unroll 1
  for (int ci = 0; ci < 4; ++ci) {
    float p[16];
    #pragma unroll
    for (int r = 0; r < 4; ++r) {
      int iy = 2 * py + r - 1;
      #pragma unroll
      for (int cx = 0; cx < 4; ++cx) {
        int ix = 2 * px + cx - 1;
        bool ok = ((unsigned)iy < 10u) && ((unsigned)ix < 10u);   // wave-uniform
        p[r * 4 + cx] = ok ? obsT[(size_t)(ci * 100 + iy * 10 + ix) * GT + g] : 0.f;
      }
    }
    #pragma unroll
    for (int t9 = 0; t9 < 9; ++t9) {
      int ky = t9 / 3, kx = t9 % 3;
      const float* w = wT + ((ci * 9 + t9) << 4);
      float wv[16];
      #pragma unroll
      for (int c = 0; c < 16; ++c) wv[c] = w[c];
      #pragma unroll
      for (int dy = 0; dy < 2; ++dy)
        #pragma unroll
        for (int dx = 0; dx < 2; ++dx) {
          float xv = p[(dy + ky) * 4 + (dx + kx)];
          #pragma unroll
          for (int c = 0; c < 16; ++c)
            acc[dy * 2 + dx][c] = fmaf(wv[c], xv, acc[dy * 2 + dx][c]);
        }
    }
  }
  #pragma unroll
  for (int c = 0; c < 16; ++c) {
    float m = fmaxf(fmaxf(acc[0][c], acc[1][c]), fmaxf(acc[2][c], acc[3][c]));
    m = fmaxf(m + bias[c], 0.f);
    pool1[(size_t)(c * 25 + pos) * GT + g] = m;
  }
}

// ---------------- conv2 (16->32, 3x3 SAME on 5x5) + relu + maxpool2(floor) ----------------
__global__ __launch_bounds__(256) void k_conv2(const float* __restrict__ pool1,
                                               const float* __restrict__ wT,
                                               const float* __restrict__ bias,
                                               float* __restrict__ pool2) {
  int g = blockIdx.x * 256 + threadIdx.x;
  int pos = blockIdx.y & 3;
  int h = blockIdx.y >> 2;
  int py = pos >> 1, px = pos & 1;
  float acc[4][16];
  #pragma unroll
  for (int s = 0; s < 4; ++s)
    #pragma unroll
    for (int c = 0; c < 16; ++c) acc[s][c] = 0.f;

  #pragma unroll 1
  for (int ci = 0; ci < 16; ++ci) {
    float p[16];
    #pragma unroll
    for (int r = 0; r < 4; ++r) {
      int iy = 2 * py + r - 1;
      #pragma unroll
      for (int cx = 0; cx < 4; ++cx) {
        int ix = 2 * px + cx - 1;
        bool ok = ((unsigned)iy < 5u) && ((unsigned)ix < 5u);     // wave-uniform
        p[r * 4 + cx] = ok ? pool1[(size_t)(ci * 25 + iy * 5 + ix) * GT + g] : 0.f;
      }
    }
    #pragma unroll
    for (int t9 = 0; t9 < 9; ++t9) {
      int ky = t9 / 3, kx = t9 % 3;
      const float* w = wT + (ci * 9 + t9) * 32 + h * 16;
      float wv[16];
      #pragma unroll
      for (int c = 0; c < 16; ++c) wv[c] = w[c];
      #pragma unroll
      for (int dy = 0; dy < 2; ++dy)
        #pragma unroll
        for (int dx = 0; dx < 2; ++dx) {
          float xv = p[(dy + ky) * 4 + (dx + kx)];
          #pragma unroll
          for (int c = 0; c < 16; ++c)
            acc[dy * 2 + dx][c] = fmaf(wv[c], xv, acc[dy * 2 + dx][c]);
        }
    }
  }
  #pragma unroll
  for (int c = 0; c < 16; ++c) {
    float m = fmaxf(fmaxf(acc[0][c], acc[1][c]), fmaxf(acc[2][c], acc[3][c]));
    m = fmaxf(m + bias[h * 16 + c], 0.f);
    int cp2 = (h * 16 + c) * 4 + pos;
    pool2[(size_t)cp2 * GT + g] = m;
  }
}

// ---------------- FC (+folded BN) + relu, 16 outputs/thread ----------------
__global__ __launch_bounds__(256) void k_fc16(const float* __restrict__ x,
                                              const float* __restrict__ WT,
                                              const float* __restrict__ bf,
                                              float* __restrict__ y, int K, int J) {
  int g = blockIdx.x * 256 + threadIdx.x;
  int j0 = blockIdx.y * 16;
  float acc[16];
  #pragma unroll
  for (int c = 0; c < 16; ++c) acc[c] = 0.f;
  for (int k = 0; k < K; ++k) {
    float xv = x[(size_t)k * GT + g];
    const float* w = WT + (size_t)k * J + j0;
    #pragma unroll
    for (int c = 0; c < 16; ++c) acc[c] = fmaf(w[c], xv, acc[c]);
  }
  #pragma unroll
  for (int c = 0; c < 16; ++c)
    y[(size_t)(j0 + c) * GT + g] = fmaxf(acc[c] + bf[j0 + c], 0.f);
}

// ---------------- encoder x-projection for ALL timesteps (parallel, bias folded) ----
// gx[t][b][512]
__global__ __launch_bounds__(256) void k_xgates(const float* __restrict__ feats,
                                                const float* __restrict__ WT,
                                                const float* __restrict__ br,
                                                float* __restrict__ gx0,
                                                float* __restrict__ gx1) {
  int t  = blockIdx.x >> 2;
  int bq = blockIdx.x & 3;
  int b  = bq * 256 + threadIdx.x;
  int r0 = blockIdx.y * 32;
  float acc[32];
  #pragma unroll
  for (int i = 0; i < 32; ++i) acc[i] = br[r0 + i];
  const float* xcol = feats + (size_t)t * 1024 + b;
  for (int k = 0; k < 64; ++k) {
    float xv = xcol[(size_t)k * GT];
    const float* w = WT + k * 512 + r0;
    #pragma unroll
    for (int i = 0; i < 32; ++i) acc[i] = fmaf(w[i], xv, acc[i]);
  }
  float* gxs = (t < 25) ? (gx0 + (size_t)t * 524288)
                        : (gx1 + (size_t)(t - 25) * 524288);
  #pragma unroll
  for (int i = 0; i < 32; ++i) gxs[(size_t)b * 512 + r0 + i] = acc[i];
}

// ---------------- fused enc+dec+head, REGISTER-RESIDENT weights ----------
// 256 blocks x 256 threads, 1 block/CU, 1 wave/SIMD (weights pinned in VGPRs).
// Thread (kg = tid&3, g = tid>>2): owns gate-rows r0=g*8..+7 and k-slice
// [kg*32, kg*32+32). Computes partial gates for all 4 batch elems of the
// block over its k-slice (1024 FMA, zero memory in the loop), then a 4-lane
// shuffle tree leaves lane kg with the full gates for batch bl=kg.
// h double-buffered in LDS: [bl][kg-slice] with slice stride 36 (bl stride
// 144) -> the 4 distinct ds_read_b128 addrs hit banks {0-3,4-7,8-11,12-15}.
__global__ __launch_bounds__(256, 1) void k_seq3(
    const float* __restrict__ gx0, const float* __restrict__ gx1,
    const float* __restrict__ WENC, const float* __restrict__ WDEC,
    const float* __restrict__ bdec,
    const float* __restrict__ ow, const float* __restrict__ ob,
    float* __restrict__ out) {
  const int tid = threadIdx.x;
  const int kg  = tid & 3;            // k-slice / owned-batch lane
  const int g   = tid >> 2;           // 0..63 row group
  const int gm  = g & 15;
  const int w   = g >> 4;             // wave index
  const int r0  = g * 8;
  const int bown = blockIdx.x * 4 + kg;   // batch element this lane finalizes

  __shared__ float hbuf[2][576];      // [buf][bl*144 + slice*36 + j]
  __shared__ float owl[12 * 132];     // padded out_w rows

  for (int i = tid; i < 576; i += 256) hbuf[0][i] = 0.f;
  for (int i = tid; i < 1536; i += 256) owl[(i >> 7) * 132 + (i & 127)] = ow[i];
  const float obv = (tid < 48) ? ob[tid >> 2] : 0.f;

  // ---- load encoder h-part weight slice into registers (once) ----
  float4 w4[64];                      // w4[k*2+rh] = W[(kbase+kg*32+k)][r0+rh*4..+3]
  #pragma unroll
  for (int k = 0; k < 32; ++k) {
    const float* wp = WENC + (size_t)(64 + kg * 32 + k) * 512 + r0;
    w4[k * 2]     = *(const float4*)wp;
    w4[k * 2 + 1] = *(const float4*)(wp + 4);
  }

  float c0 = 0.f, c1 = 0.f;
  const int rdofs = kg * 36;              // this lane's k-slice base in a bl row
  const int wrofs = kg * 144 + w * 36 + 2 * gm;  // write addr for h (bl=kg, units 2g,2g+1)
  __syncthreads();

  int cur = 0;

  // ================= encoder: 32 steps =================
  for (int t = 0; t < TSEQ; ++t) {
    // gx for my owned batch (issued early; consumed after the FMA chain)
    const float* gxs = (t < 25) ? (gx0 + (size_t)t * 524288)
                                : (gx1 + (size_t)(t - 25) * 524288);
    const float4 ga = *(const float4*)(gxs + (size_t)bown * 512 + r0);
    const float4 gb = *(const float4*)(gxs + (size_t)bown * 512 + r0 + 4);

    float acc[4][8];
    #pragma unroll
    for (int bl = 0; bl < 4; ++bl)
      #pragma unroll
      for (int r = 0; r < 8; ++r) acc[bl][r] = 0.f;

    const float* hc = &hbuf[cur][0];
    #pragma unroll
    for (int k4 = 0; k4 < 8; ++k4) {
      float4 h4[4];
      #pragma unroll
      for (int bl = 0; bl < 4; ++bl)
        h4[bl] = *(const float4*)&hc[bl * 144 + rdofs + k4 * 4];
      #pragma unroll
      for (int kj = 0; kj < 4; ++kj) {
        const float4 wa = w4[(k4 * 4 + kj) * 2];
        const float4 wb = w4[(k4 * 4 + kj) * 2 + 1];
        #pragma unroll
        for (int bl = 0; bl < 4; ++bl) {
          const float hv = (&h4[bl].x)[kj];
          acc[bl][0] = fmaf(wa.x, hv, acc[bl][0]);
          acc[bl][1] = fmaf(wa.y, hv, acc[bl][1]);
          acc[bl][2] = fmaf(wa.z, hv, acc[bl][2]);
          acc[bl][3] = fmaf(wa.w, hv, acc[bl][3]);
          acc[bl][4] = fmaf(wb.x, hv, acc[bl][4]);
          acc[bl][5] = fmaf(wb.y, hv, acc[bl][5]);
          acc[bl][6] = fmaf(wb.z, hv, acc[bl][6]);
          acc[bl][7] = fmaf(wb.w, hv, acc[bl][7]);
        }
      }
    }
    // ---- 4-lane reduce, keep bl = kg (no dynamic register indexing) ----
    float s2[2][8], D[8];
    #pragma unroll
    for (int r = 0; r < 8; ++r) {
      float a0 = acc[0][r] + __shfl_xor(acc[0][r], 1, 64);
      float a1 = acc[1][r] + __shfl_xor(acc[1][r], 1, 64);
      float a2 = acc[2][r] + __shfl_xor(acc[2][r], 1, 64);
      float a3 = acc[3][r] + __shfl_xor(acc[3][r], 1, 64);
      s2[0][r] = (kg & 1) ? a1 : a0;
      s2[1][r] = (kg & 1) ? a3 : a2;
    }
    #pragma unroll
    for (int r = 0; r < 8; ++r) {
      float t0 = s2[0][r] + __shfl_xor(s2[0][r], 2, 64);
      float t1 = s2[1][r] + __shfl_xor(s2[1][r], 2, 64);
      D[r] = (kg & 2) ? t1 : t0;
    }
    // gates = reduced h-part + precomputed x-part (bias folded in gx)
    const float gi0 = D[0] + ga.x, gf0 = D[1] + ga.y, gg0 = D[2] + ga.z, go0 = D[3] + ga.w;
    const float gi1 = D[4] + gb.x, gf1 = D[5] + gb.y, gg1 = D[6] + gb.z, go1 = D[7] + gb.w;
    c0 = sigf(gf0) * c0 + sigf(gi0) * tanhfast(gg0);
    c1 = sigf(gf1) * c1 + sigf(gi1) * tanhfast(gg1);
    const float hn0 = sigf(go0) * tanhfast(c0);
    const float hn1 = sigf(go1) * tanhfast(c1);
    *(float2*)&hbuf[cur ^ 1][wrofs] = make_float2(hn0, hn1);
    __syncthreads();
    cur ^= 1;
  }

  // ---- swap in decoder weights (x_in == h => W = W_ih + W_hh, pre-summed) ----
  #pragma unroll
  for (int k = 0; k < 32; ++k) {
    const float* wp = WDEC + (size_t)(kg * 32 + k) * 512 + r0;
    w4[k * 2]     = *(const float4*)wp;
    w4[k * 2 + 1] = *(const float4*)(wp + 4);
  }
  const float4 bda = *(const float4*)(bdec + r0);
  const float4 bdb = *(const float4*)(bdec + r0 + 4);

  // ================= decoder: 10 steps + fused head =================
  for (int t = 0; t < 10; ++t) {
    float acc[4][8];
    #pragma unroll
    for (int bl = 0; bl < 4; ++bl)
      #pragma unroll
      for (int r = 0; r < 8; ++r) acc[bl][r] = 0.f;

    const float* hc = &hbuf[cur][0];
    #pragma unroll
    for (int k4 = 0; k4 < 8; ++k4) {
      float4 h4[4];
      #pragma unroll
      for (int bl = 0; bl < 4; ++bl)
        h4[bl] = *(const float4*)&hc[bl * 144 + rdofs + k4 * 4];
      #pragma unroll
      for (int kj = 0; kj < 4; ++kj) {
        const float4 wa = w4[(k4 * 4 + kj) * 2];
        const float4 wb = w4[(k4 * 4 + kj) * 2 + 1];
        #pragma unroll
        for (int bl = 0; bl < 4; ++bl) {
          const float hv = (&h4[bl].x)[kj];
          acc[bl][0] = fmaf(wa.x, hv, acc[bl][0]);
          acc[bl][1] = fmaf(wa.y, hv, acc[bl][1]);
          acc[bl][2] = fmaf(wa.z, hv, acc[bl][2]);
          acc[bl][3] = fmaf(wa.w, hv, acc[bl][3]);
          acc[bl][4] = fmaf(wb.x, hv, acc[bl][4]);
          acc[bl][5] = fmaf(wb.y, hv, acc[bl][5]);
          acc[bl][6] = fmaf(wb.z, hv, acc[bl][6]);
          acc[bl][7] = fmaf(wb.w, hv, acc[bl][7]);
        }
      }
    }
    float s2[2][8], D[8];
    #pragma unroll
    for (int r = 0; r < 8; ++r) {
      float a0 = acc[0][r] + __shfl_xor(acc[0][r], 1, 64);
      float a1 = acc[1][r] + __shfl_xor(acc[1][r], 1, 64);
      float a2 = acc[2][r] + __shfl_xor(acc[2][r], 1, 64);
      float a3 = acc[3][r] + __shfl_xor(acc[3][r], 1, 64);
      s2[0][r] = (kg & 1) ? a1 : a0;
      s2[1][r] = (kg & 1) ? a3 : a2;
    }
    #pragma unroll
    for (int r = 0; r < 8; ++r) {
      float t0 = s2[0][r] + __shfl_xor(s2[0][r], 2, 64);
      float t1 = s2[1][r] + __shfl_xor(s2[1][r], 2, 64);
      D[r] = (kg & 2) ? t1 : t0;
    }
    const float gi0 = D[0] + bda.x, gf0 = D[1] + bda.y, gg0 = D[2] + bda.z, go0 = D[3] + bda.w;
    const float gi1 = D[4] + bdb.x, gf1 = D[5] + bdb.y, gg1 = D[6] + bdb.z, go1 = D[7] + bdb.w;
    c0 = sigf(gf0) * c0 + sigf(gi0) * tanhfast(gg0);
    c1 = sigf(gf1) * c1 + sigf(gi1) * tanhfast(gg1);
    const float hn0 = sigf(go0) * tanhfast(c0);
    const float hn1 = sigf(go1) * tanhfast(c1);
    *(float2*)&hbuf[cur ^ 1][wrofs] = make_float2(hn0, hn1);
    __syncthreads();
    cur ^= 1;
    // output head for this step's new h: tid<48 (o = tid>>2, bl = tid&3), LDS only
    if (tid < 48) {
      const int o  = tid >> 2;
      const int bh = tid & 3;
      const float* hh = &hbuf[cur][bh * 144];
      const float* wo = &owl[o * 132];
      float oacc = obv;
      #pragma unroll
      for (int k4 = 0; k4 < 32; ++k4) {
        const float4 hv4 = *(const float4*)&hh[(k4 >> 3) * 36 + (k4 & 7) * 4];
        const int kb = k4 * 4;
        oacc = fmaf(wo[kb + 0], hv4.x, oacc);
        oacc = fmaf(wo[kb + 1], hv4.y, oacc);
        oacc = fmaf(wo[kb + 2], hv4.z, oacc);
        oacc = fmaf(wo[kb + 3], hv4.w, oacc);
      }
      out[(blockIdx.x * 4 + bh) * 120 + t * 12 + o] = oacc;
    }
  }
}

// ---------------- launch ----------------
extern "C" void kernel_launch(void* const* d_in, const int* in_sizes, int n_in,
                              void* d_out, int out_size, void* d_ws, size_t ws_size,
                              hipStream_t stream) {
  const float* obs  = (const float*)d_in[0];
  const float* c1w  = (const float*)d_in[1];
  const float* c1b  = (const float*)d_in[2];
  const float* c2w  = (const float*)d_in[3];
  const float* c2b  = (const float*)d_in[4];
  const float* f1w  = (const float*)d_in[5];
  const float* f1b  = (const float*)d_in[6];
  const float* g1   = (const float*)d_in[7];
  const float* be1  = (const float*)d_in[8];
  const float* m1   = (const float*)d_in[9];
  const float* v1   = (const float*)d_in[10];
  const float* f2w  = (const float*)d_in[11];
  const float* f2b  = (const float*)d_in[12];
  const float* g2   = (const float*)d_in[13];
  const float* be2  = (const float*)d_in[14];
  const float* m2   = (const float*)d_in[15];
  const float* v2   = (const float*)d_in[16];
  const float* ewih = (const float*)d_in[17];
  const float* ewhh = (const float*)d_in[18];
  const float* eb   = (const float*)d_in[19];
  const float* dwih = (const float*)d_in[20];
  const float* dwhh = (const float*)d_in[21];
  const float* db   = (const float*)d_in[22];
  const float* ow   = (const float*)d_in[23];
  const float* ob   = (const float*)d_in[24];
  float* ws  = (float*)d_ws;
  float* out = (float*)d_out;

  k_setup<<<761, 256, 0, stream>>>(c1w, c2w, f1w, f1b, g1, be1, m1, v1,
                                   f2w, f2b, g2, be2, m2, v2,
                                   ewih, ewhh, eb, dwih, dwhh, db, ws);
  k_transpose<<<dim3(200, 16), 256, 0, stream>>>(obs, ws + OBS_T);
  k_conv1<<<dim3(128, 25), 256, 0, stream>>>(ws + OBS_T, ws + W_C1, c1b, ws + POOL1);
  k_conv2<<<dim3(128, 8), 256, 0, stream>>>(ws + POOL1, ws + W_C2, c2b, ws + POOL2);
  k_fc16<<<dim3(128, 8), 256, 0, stream>>>(ws + POOL2, ws + W_F1, ws + B_F1, ws + Y1, 128, 128);
  k_fc16<<<dim3(128, 4), 256, 0, stream>>>(ws + Y1, ws + W_F2, ws + B_F2, ws + FEATS, 128, 64);
  k_xgates<<<dim3(128, 16), 256, 0, stream>>>(ws + FEATS, ws + W_ENC, ws + B_ENC,
                                              ws + GX0, ws + GX1);
  // fused encoder + decoder + output head: register-resident weights
  k_seq3<<<256, 256, 0, stream>>>(ws + GX0, ws + GX1, ws + W_ENC, ws + W_DEC,
                                  ws + B_DEC, ow, ob, out);
}

// Round 7
// 479.528 us; speedup vs baseline: 7.0162x; 1.2216x over previous
//
#include <hip/hip_runtime.h>
#include <hip/hip_bf16.h>

// ---------------- problem constants ----------------
constexpr int GT = 32768;          // B*T frames
constexpr int TSEQ = 32;

// ---------------- workspace layout (floats) ----------------
constexpr size_t OBS_T = 0;
constexpr size_t POOL1 = 13107200;
constexpr size_t POOL2 = 0;
constexpr size_t Y1    = 4194304;
constexpr size_t FEATS = 13107200;
constexpr size_t GX0   = 0;                 // t<25, layout [t][b][512]
constexpr size_t GX1   = 15204352;          // t>=25
constexpr size_t WB    = 26214400;          // weights region
constexpr size_t W_C1  = WB + 0;            // 576   : conv1 wT [36][16]
constexpr size_t W_C2  = WB + 576;          // 4608  : conv2 wT [144][32]
constexpr size_t W_F1  = WB + 5184;         // 16384 : fc1 wT [128][128], BN folded
constexpr size_t B_F1  = WB + 21568;        // 128
constexpr size_t W_F2  = WB + 21696;        // 8192  : fc2 wT [128][64], BN folded
constexpr size_t B_F2  = WB + 29888;        // 64
constexpr size_t W_ENC = WB + 29952;        // 98304 : enc wT [192][512], rows r=u*4+gate
constexpr size_t B_ENC = WB + 128256;       // 512
constexpr size_t W_DEC = WB + 128768;       // 65536 : (dec_w_ih+dec_w_hh) wT [128][512]
constexpr size_t B_DEC = WB + 194304;       // 512

__device__ __forceinline__ float sigf(float x)  { return 1.f / (1.f + __expf(-x)); }
__device__ __forceinline__ float tanhfast(float x) { return 1.f - 2.f / (__expf(2.f * x) + 1.f); }

// ---------------- setup: transpose/fold weights ----------
__global__ __launch_bounds__(256) void k_setup(
    const float* __restrict__ c1w, const float* __restrict__ c2w,
    const float* __restrict__ f1w, const float* __restrict__ f1b,
    const float* __restrict__ g1, const float* __restrict__ be1,
    const float* __restrict__ m1, const float* __restrict__ v1,
    const float* __restrict__ f2w, const float* __restrict__ f2b,
    const float* __restrict__ g2, const float* __restrict__ be2,
    const float* __restrict__ m2, const float* __restrict__ v2,
    const float* __restrict__ ewih, const float* __restrict__ ewhh, const float* __restrict__ eb,
    const float* __restrict__ dwih, const float* __restrict__ dwhh, const float* __restrict__ db,
    float* __restrict__ ws) {
  long i = (long)blockIdx.x * 256 + threadIdx.x;
  if (i < 576)  { int c = i & 15, r = i >> 4; ws[W_C1 + i] = c1w[c * 36 + r]; return; }
  i -= 576;
  if (i < 4608) { int c = i & 31, r = i >> 5; ws[W_C2 + i] = c2w[c * 144 + r]; return; }
  i -= 4608;
  if (i < 16384) { int j = i & 127, k = i >> 7;
    float s = g1[j] * rsqrtf(v1[j] + 1e-5f);
    ws[W_F1 + i] = f1w[j * 128 + k] * s; return; }
  i -= 16384;
  if (i < 128) { int j = i; float s = g1[j] * rsqrtf(v1[j] + 1e-5f);
    ws[B_F1 + i] = (f1b[j] - m1[j]) * s + be1[j]; return; }
  i -= 128;
  if (i < 8192) { int j = i & 63, k = i >> 6;
    float s = g2[j] * rsqrtf(v2[j] + 1e-5f);
    ws[W_F2 + i] = f2w[j * 128 + k] * s; return; }
  i -= 8192;
  if (i < 64) { int j = i; float s = g2[j] * rsqrtf(v2[j] + 1e-5f);
    ws[B_F2 + i] = (f2b[j] - m2[j]) * s + be2[j]; return; }
  i -= 64;
  if (i < 98304) { int r = i & 511, k = i >> 9;
    int u = r >> 2, gt = r & 3, jr = gt * 128 + u;
    ws[W_ENC + i] = (k < 64) ? ewih[jr * 64 + k] : ewhh[jr * 128 + (k - 64)]; return; }
  i -= 98304;
  if (i < 512) { int u = i >> 2, gt = i & 3; ws[B_ENC + i] = eb[gt * 128 + u]; return; }
  i -= 512;
  if (i < 65536) { int r = i & 511, k = i >> 9;
    int u = r >> 2, gt = r & 3, jr = gt * 128 + u;
    ws[W_DEC + i] = dwih[jr * 128 + k] + dwhh[jr * 128 + k]; return; }
  i -= 65536;
  if (i < 512) { int u = i >> 2, gt = i & 3; ws[B_DEC + i] = db[gt * 128 + u]; return; }
}

// ---------------- transpose obs [b][tp] -> obsT [p][t][b], float4 loads ----------------
__global__ __launch_bounds__(256) void k_transpose(const float* __restrict__ obs,
                                                   float* __restrict__ obsT) {
  __shared__ float tile[64][65];
  int tp0 = blockIdx.x * 64;
  int b0  = blockIdx.y * 64;
  int q     = threadIdx.x & 15;
  int rbase = threadIdx.x >> 4;
  #pragma unroll
  for (int rr = 0; rr < 4; ++rr) {
    int row = rbase + rr * 16;
    const float4 v = *(const float4*)(obs + (size_t)(b0 + row) * 12800 + tp0 + q * 4);
    tile[row][q * 4 + 0] = v.x;
    tile[row][q * 4 + 1] = v.y;
    tile[row][q * 4 + 2] = v.z;
    tile[row][q * 4 + 3] = v.w;
  }
  __syncthreads();
  int lane = threadIdx.x & 63;
  int grp  = threadIdx.x >> 6;
  for (int cc = 0; cc < 16; ++cc) {
    int col = grp * 16 + cc;
    int tp = tp0 + col;
    int t = tp / 400, p = tp % 400;
    obsT[(size_t)p * GT + t * 1024 + b0 + lane] = tile[lane][col];
  }
}

// ---------------- conv1 (4->16, 3x3 SAME on 10x10) + relu + maxpool2 ----------------
__global__ __launch_bounds__(256) void k_conv1(const float* __restrict__ obsT,
                                               const float* __restrict__ wT,
                                               const float* __restrict__ bias,
                                               float* __restrict__ pool1) {
  int g = blockIdx.x * 256 + threadIdx.x;
  int pos = blockIdx.y;
  int py = pos / 5, px = pos % 5;
  float acc[4][16];
  #pragma unroll
  for (int s = 0; s < 4; ++s)
    #pragma unroll
    for (int c = 0; c < 16; ++c) acc[s][c] = 0.f;

  #pragma unroll 1
  for (int ci = 0; ci < 4; ++ci) {
    float p[16];
    #pragma unroll
    for (int r = 0; r < 4; ++r) {
      int iy = 2 * py + r - 1;
      #pragma unroll
      for (int cx = 0; cx < 4; ++cx) {
        int ix = 2 * px + cx - 1;
        bool ok = ((unsigned)iy < 10u) && ((unsigned)ix < 10u);   // wave-uniform
        p[r * 4 + cx] = ok ? obsT[(size_t)(ci * 100 + iy * 10 + ix) * GT + g] : 0.f;
      }
    }
    #pragma unroll
    for (int t9 = 0; t9 < 9; ++t9) {
      int ky = t9 / 3, kx = t9 % 3;
      const float* w = wT + ((ci * 9 + t9) << 4);
      float wv[16];
      #pragma unroll
      for (int c = 0; c < 16; ++c) wv[c] = w[c];
      #pragma unroll
      for (int dy = 0; dy < 2; ++dy)
        #pragma unroll
        for (int dx = 0; dx < 2; ++dx) {
          float xv = p[(dy + ky) * 4 + (dx + kx)];
          #pragma unroll
          for (int c = 0; c < 16; ++c)
            acc[dy * 2 + dx][c] = fmaf(wv[c], xv, acc[dy * 2 + dx][c]);
        }
    }
  }
  #pragma unroll
  for (int c = 0; c < 16; ++c) {
    float m = fmaxf(fmaxf(acc[0][c], acc[1][c]), fmaxf(acc[2][c], acc[3][c]));
    m = fmaxf(m + bias[c], 0.f);
    pool1[(size_t)(c * 25 + pos) * GT + g] = m;
  }
}

// ---------------- conv2 (16->32) + relu + maxpool2: 8 c_out per thread, 2048 blocks ----
__global__ __launch_bounds__(256) void k_conv2(const float* __restrict__ pool1,
                                               const float* __restrict__ wT,
                                               const float* __restrict__ bias,
                                               float* __restrict__ pool2) {
  int g = blockIdx.x * 256 + threadIdx.x;
  int pos = blockIdx.y & 3;
  int h = blockIdx.y >> 2;              // c_out quarter (0..3), 8 channels each
  int py = pos >> 1, px = pos & 1;
  float acc[4][8];
  #pragma unroll
  for (int s = 0; s < 4; ++s)
    #pragma unroll
    for (int c = 0; c < 8; ++c) acc[s][c] = 0.f;

  #pragma unroll 1
  for (int ci = 0; ci < 16; ++ci) {
    float p[16];
    #pragma unroll
    for (int r = 0; r < 4; ++r) {
      int iy = 2 * py + r - 1;
      #pragma unroll
      for (int cx = 0; cx < 4; ++cx) {
        int ix = 2 * px + cx - 1;
        bool ok = ((unsigned)iy < 5u) && ((unsigned)ix < 5u);     // wave-uniform
        p[r * 4 + cx] = ok ? pool1[(size_t)(ci * 25 + iy * 5 + ix) * GT + g] : 0.f;
      }
    }
    #pragma unroll
    for (int t9 = 0; t9 < 9; ++t9) {
      int ky = t9 / 3, kx = t9 % 3;
      const float* w = wT + (ci * 9 + t9) * 32 + h * 8;
      float wv[8];
      #pragma unroll
      for (int c = 0; c < 8; ++c) wv[c] = w[c];
      #pragma unroll
      for (int dy = 0; dy < 2; ++dy)
        #pragma unroll
        for (int dx = 0; dx < 2; ++dx) {
          float xv = p[(dy + ky) * 4 + (dx + kx)];
          #pragma unroll
          for (int c = 0; c < 8; ++c)
            acc[dy * 2 + dx][c] = fmaf(wv[c], xv, acc[dy * 2 + dx][c]);
        }
    }
  }
  #pragma unroll
  for (int c = 0; c < 8; ++c) {
    float m = fmaxf(fmaxf(acc[0][c], acc[1][c]), fmaxf(acc[2][c], acc[3][c]));
    m = fmaxf(m + bias[h * 8 + c], 0.f);
    int cp2 = (h * 8 + c) * 4 + pos;
    pool2[(size_t)cp2 * GT + g] = m;
  }
}

// ---------------- FC (+folded BN) + relu, 16 outputs/thread ----------------
__global__ __launch_bounds__(256) void k_fc16(const float* __restrict__ x,
                                              const float* __restrict__ WT,
                                              const float* __restrict__ bf,
                                              float* __restrict__ y, int K, int J) {
  int g = blockIdx.x * 256 + threadIdx.x;
  int j0 = blockIdx.y * 16;
  float acc[16];
  #pragma unroll
  for (int c = 0; c < 16; ++c) acc[c] = 0.f;
  for (int k = 0; k < K; ++k) {
    float xv = x[(size_t)k * GT + g];
    const float* w = WT + (size_t)k * J + j0;
    #pragma unroll
    for (int c = 0; c < 16; ++c) acc[c] = fmaf(w[c], xv, acc[c]);
  }
  #pragma unroll
  for (int c = 0; c < 16; ++c)
    y[(size_t)(j0 + c) * GT + g] = fmaxf(acc[c] + bf[j0 + c], 0.f);
}

// ---------------- encoder x-projection for ALL timesteps (parallel, bias folded) ----
// gx[t][b][512]
__global__ __launch_bounds__(256) void k_xgates(const float* __restrict__ feats,
                                                const float* __restrict__ WT,
                                                const float* __restrict__ br,
                                                float* __restrict__ gx0,
                                                float* __restrict__ gx1) {
  int t  = blockIdx.x >> 2;
  int bq = blockIdx.x & 3;
  int b  = bq * 256 + threadIdx.x;
  int r0 = blockIdx.y * 32;
  float acc[32];
  #pragma unroll
  for (int i = 0; i < 32; ++i) acc[i] = br[r0 + i];
  const float* xcol = feats + (size_t)t * 1024 + b;
  for (int k = 0; k < 64; ++k) {
    float xv = xcol[(size_t)k * GT];
    const float* w = WT + k * 512 + r0;
    #pragma unroll
    for (int i = 0; i < 32; ++i) acc[i] = fmaf(w[i], xv, acc[i]);
  }
  float* gxs = (t < 25) ? (gx0 + (size_t)t * 524288)
                        : (gx1 + (size_t)(t - 25) * 524288);
  #pragma unroll
  for (int i = 0; i < 32; ++i) gxs[(size_t)b * 512 + r0 + i] = acc[i];
}

// ---------------- fused enc+dec+head, register-resident weights, 8-way k-split ------
// 256 blocks x 512 threads, 4 batch/block  (256*4 = 1024 = full batch!).
// Thread (kg = tid&7, g = tid>>3): gate rows r0=g*8..+7, k-slice [kg*16, +16)
// -> 128 weight VGPRs/thread. Per step: 4 bl x 8 r x 16 k = 512 FMA (device-wide
// exactly one copy of the 67M MACs), then 3 shuffle rounds: xor1 select kg&1,
// xor2 select kg&2, xor4 plain add -> lane kg holds full gates for bl = kg&3
// (duplicated over kg>>2). Lanes kg<4 write h to LDS. One barrier per step.
constexpr int HSTR = 132;   // LDS h row stride per batch elem
__global__ __launch_bounds__(512, 2) void k_seq5(
    const float* __restrict__ gx0, const float* __restrict__ gx1,
    const float* __restrict__ WENC, const float* __restrict__ WDEC,
    const float* __restrict__ bdec,
    const float* __restrict__ ow, const float* __restrict__ ob,
    float* __restrict__ out) {
  const int tid = threadIdx.x;
  const int kg  = tid & 7;            // k-slice lane
  const int g   = tid >> 3;           // 0..63 row group
  const int r0  = g * 8;
  const int blo = kg & 3;             // batch elem this lane finalizes
  const int bown = blockIdx.x * 4 + blo;

  __shared__ float hbuf[2][4 * HSTR]; // [buf][bl*HSTR + k]
  __shared__ float owl[12 * HSTR];    // padded out_w rows

  for (int i = tid; i < 2 * 4 * HSTR; i += 512) hbuf[i / (4 * HSTR)][i % (4 * HSTR)] = 0.f;
  for (int i = tid; i < 1536; i += 512) owl[(i >> 7) * HSTR + (i & 127)] = ow[i];
  const float obv = (tid < 48) ? ob[tid >> 2] : 0.f;

  // ---- encoder h-part weight slice -> registers (once) ----
  float4 w4[32];                      // w4[k*2+hh] = W[(kbase + kg*16 + k)][r0 + hh*4 ..]
  #pragma unroll
  for (int k = 0; k < 16; ++k) {
    const float* wp = WENC + (size_t)(64 + kg * 16 + k) * 512 + r0;
    w4[k * 2]     = *(const float4*)wp;
    w4[k * 2 + 1] = *(const float4*)(wp + 4);
  }

  float c0 = 0.f, c1 = 0.f;
  const int rdofs = kg * 16;                    // k-slice base within a bl row
  const int wrofs = blo * HSTR + g * 2;         // h write addr (units 2g, 2g+1), kg<4
  __syncthreads();

  int cur = 0;

  // ================= encoder: 32 steps =================
  for (int t = 0; t < TSEQ; ++t) {
    const float* gxs = (t < 25) ? (gx0 + (size_t)t * 524288)
                                : (gx1 + (size_t)(t - 25) * 524288);
    const float4 ga = *(const float4*)(gxs + (size_t)bown * 512 + r0);
    const float4 gb = *(const float4*)(gxs + (size_t)bown * 512 + r0 + 4);

    float acc[4][8];
    #pragma unroll
    for (int bl = 0; bl < 4; ++bl)
      #pragma unroll
      for (int r = 0; r < 8; ++r) acc[bl][r] = 0.f;

    const float* hc = &hbuf[cur][0];
    #pragma unroll
    for (int k4 = 0; k4 < 4; ++k4) {
      float4 h4[4];
      #pragma unroll
      for (int bl = 0; bl < 4; ++bl)
        h4[bl] = *(const float4*)&hc[bl * HSTR + rdofs + k4 * 4];
      #pragma unroll
      for (int kj = 0; kj < 4; ++kj) {
        const float4 wa = w4[(k4 * 4 + kj) * 2];
        const float4 wb = w4[(k4 * 4 + kj) * 2 + 1];
        #pragma unroll
        for (int bl = 0; bl < 4; ++bl) {
          const float hv = (&h4[bl].x)[kj];
          acc[bl][0] = fmaf(wa.x, hv, acc[bl][0]);
          acc[bl][1] = fmaf(wa.y, hv, acc[bl][1]);
          acc[bl][2] = fmaf(wa.z, hv, acc[bl][2]);
          acc[bl][3] = fmaf(wa.w, hv, acc[bl][3]);
          acc[bl][4] = fmaf(wb.x, hv, acc[bl][4]);
          acc[bl][5] = fmaf(wb.y, hv, acc[bl][5]);
          acc[bl][6] = fmaf(wb.z, hv, acc[bl][6]);
          acc[bl][7] = fmaf(wb.w, hv, acc[bl][7]);
        }
      }
    }
    // ---- 8-lane reduce with batch routing: xor1(sel kg&1), xor2(sel kg&2), xor4 ----
    float D[8];
    #pragma unroll
    for (int r = 0; r < 8; ++r) {
      float a0 = acc[0][r] + __shfl_xor(acc[0][r], 1, 64);
      float a1 = acc[1][r] + __shfl_xor(acc[1][r], 1, 64);
      float a2 = acc[2][r] + __shfl_xor(acc[2][r], 1, 64);
      float a3 = acc[3][r] + __shfl_xor(acc[3][r], 1, 64);
      float sL = (kg & 1) ? a1 : a0;
      float sH = (kg & 1) ? a3 : a2;
      float tL = sL + __shfl_xor(sL, 2, 64);
      float tH = sH + __shfl_xor(sH, 2, 64);
      float s  = (kg & 2) ? tH : tL;
      s += __shfl_xor(s, 4, 64);
      D[r] = s;
    }
    const float gi0 = D[0] + ga.x, gf0 = D[1] + ga.y, gg0 = D[2] + ga.z, go0 = D[3] + ga.w;
    const float gi1 = D[4] + gb.x, gf1 = D[5] + gb.y, gg1 = D[6] + gb.z, go1 = D[7] + gb.w;
    c0 = sigf(gf0) * c0 + sigf(gi0) * tanhfast(gg0);
    c1 = sigf(gf1) * c1 + sigf(gi1) * tanhfast(gg1);
    const float hn0 = sigf(go0) * tanhfast(c0);
    const float hn1 = sigf(go1) * tanhfast(c1);
    if (kg < 4) *(float2*)&hbuf[cur ^ 1][wrofs] = make_float2(hn0, hn1);
    __syncthreads();
    cur ^= 1;
  }

  // ---- swap in decoder weights (x_in == h => W = W_ih + W_hh, pre-summed) ----
  #pragma unroll
  for (int k = 0; k < 16; ++k) {
    const float* wp = WDEC + (size_t)(kg * 16 + k) * 512 + r0;
    w4[k * 2]     = *(const float4*)wp;
    w4[k * 2 + 1] = *(const float4*)(wp + 4);
  }
  const float4 bda = *(const float4*)(bdec + r0);
  const float4 bdb = *(const float4*)(bdec + r0 + 4);

  // ================= decoder: 10 steps + fused head =================
  for (int t = 0; t < 10; ++t) {
    float acc[4][8];
    #pragma unroll
    for (int bl = 0; bl < 4; ++bl)
      #pragma unroll
      for (int r = 0; r < 8; ++r) acc[bl][r] = 0.f;

    const float* hc = &hbuf[cur][0];
    #pragma unroll
    for (int k4 = 0; k4 < 4; ++k4) {
      float4 h4[4];
      #pragma unroll
      for (int bl = 0; bl < 4; ++bl)
        h4[bl] = *(const float4*)&hc[bl * HSTR + rdofs + k4 * 4];
      #pragma unroll
      for (int kj = 0; kj < 4; ++kj) {
        const float4 wa = w4[(k4 * 4 + kj) * 2];
        const float4 wb = w4[(k4 * 4 + kj) * 2 + 1];
        #pragma unroll
        for (int bl = 0; bl < 4; ++bl) {
          const float hv = (&h4[bl].x)[kj];
          acc[bl][0] = fmaf(wa.x, hv, acc[bl][0]);
          acc[bl][1] = fmaf(wa.y, hv, acc[bl][1]);
          acc[bl][2] = fmaf(wa.z, hv, acc[bl][2]);
          acc[bl][3] = fmaf(wa.w, hv, acc[bl][3]);
          acc[bl][4] = fmaf(wb.x, hv, acc[bl][4]);
          acc[bl][5] = fmaf(wb.y, hv, acc[bl][5]);
          acc[bl][6] = fmaf(wb.z, hv, acc[bl][6]);
          acc[bl][7] = fmaf(wb.w, hv, acc[bl][7]);
        }
      }
    }
    float D[8];
    #pragma unroll
    for (int r = 0; r < 8; ++r) {
      float a0 = acc[0][r] + __shfl_xor(acc[0][r], 1, 64);
      float a1 = acc[1][r] + __shfl_xor(acc[1][r], 1, 64);
      float a2 = acc[2][r] + __shfl_xor(acc[2][r], 1, 64);
      float a3 = acc[3][r] + __shfl_xor(acc[3][r], 1, 64);
      float sL = (kg & 1) ? a1 : a0;
      float sH = (kg & 1) ? a3 : a2;
      float tL = sL + __shfl_xor(sL, 2, 64);
      float tH = sH + __shfl_xor(sH, 2, 64);
      float s  = (kg & 2) ? tH : tL;
      s += __shfl_xor(s, 4, 64);
      D[r] = s;
    }
    const float gi0 = D[0] + bda.x, gf0 = D[1] + bda.y, gg0 = D[2] + bda.z, go0 = D[3] + bda.w;
    const float gi1 = D[4] + bdb.x, gf1 = D[5] + bdb.y, gg1 = D[6] + bdb.z, go1 = D[7] + bdb.w;
    c0 = sigf(gf0) * c0 + sigf(gi0) * tanhfast(gg0);
    c1 = sigf(gf1) * c1 + sigf(gi1) * tanhfast(gg1);
    const float hn0 = sigf(go0) * tanhfast(c0);
    const float hn1 = sigf(go1) * tanhfast(c1);
    if (kg < 4) *(float2*)&hbuf[cur ^ 1][wrofs] = make_float2(hn0, hn1);
    __syncthreads();
    cur ^= 1;
    // output head: tid<48 (o = tid>>2, bl = tid&3), LDS-only reads of new h
    if (tid < 48) {
      const int o  = tid >> 2;
      const int bh = tid & 3;
      const float* hh = &hbuf[cur][bh * HSTR];
      const float* wo = &owl[o * HSTR];
      float oacc = obv;
      #pragma unroll
      for (int k4 = 0; k4 < 32; ++k4) {
        const float4 hv4 = *(const float4*)&hh[k4 * 4];
        const int kb = k4 * 4;
        oacc = fmaf(wo[kb + 0], hv4.x, oacc);
        oacc = fmaf(wo[kb + 1], hv4.y, oacc);
        oacc = fmaf(wo[kb + 2], hv4.z, oacc);
        oacc = fmaf(wo[kb + 3], hv4.w, oacc);
      }
      out[(blockIdx.x * 4 + bh) * 120 + t * 12 + o] = oacc;
    }
  }
}

// ---------------- launch ----------------
extern "C" void kernel_launch(void* const* d_in, const int* in_sizes, int n_in,
                              void* d_out, int out_size, void* d_ws, size_t ws_size,
                              hipStream_t stream) {
  const float* obs  = (const float*)d_in[0];
  const float* c1w  = (const float*)d_in[1];
  const float* c1b  = (const float*)d_in[2];
  const float* c2w  = (const float*)d_in[3];
  const float* c2b  = (const float*)d_in[4];
  const float* f1w  = (const float*)d_in[5];
  const float* f1b  = (const float*)d_in[6];
  const float* g1   = (const float*)d_in[7];
  const float* be1  = (const float*)d_in[8];
  const float* m1   = (const float*)d_in[9];
  const float* v1   = (const float*)d_in[10];
  const float* f2w  = (const float*)d_in[11];
  const float* f2b  = (const float*)d_in[12];
  const float* g2   = (const float*)d_in[13];
  const float* be2  = (const float*)d_in[14];
  const float* m2   = (const float*)d_in[15];
  const float* v2   = (const float*)d_in[16];
  const float* ewih = (const float*)d_in[17];
  const float* ewhh = (const float*)d_in[18];
  const float* eb   = (const float*)d_in[19];
  const float* dwih = (const float*)d_in[20];
  const float* dwhh = (const float*)d_in[21];
  const float* db   = (const float*)d_in[22];
  const float* ow   = (const float*)d_in[23];
  const float* ob   = (const float*)d_in[24];
  float* ws  = (float*)d_ws;
  float* out = (float*)d_out;

  k_setup<<<761, 256, 0, stream>>>(c1w, c2w, f1w, f1b, g1, be1, m1, v1,
                                   f2w, f2b, g2, be2, m2, v2,
                                   ewih, ewhh, eb, dwih, dwhh, db, ws);
  k_transpose<<<dim3(200, 16), 256, 0, stream>>>(obs, ws + OBS_T);
  k_conv1<<<dim3(128, 25), 256, 0, stream>>>(ws + OBS_T, ws + W_C1, c1b, ws + POOL1);
  k_conv2<<<dim3(128, 16), 256, 0, stream>>>(ws + POOL1, ws + W_C2, c2b, ws + POOL2);
  k_fc16<<<dim3(128, 8), 256, 0, stream>>>(ws + POOL2, ws + W_F1, ws + B_F1, ws + Y1, 128, 128);
  k_fc16<<<dim3(128, 4), 256, 0, stream>>>(ws + Y1, ws + W_F2, ws + B_F2, ws + FEATS, 128, 64);
  k_xgates<<<dim3(128, 16), 256, 0, stream>>>(ws + FEATS, ws + W_ENC, ws + B_ENC,
                                              ws + GX0, ws + GX1);
  // fused encoder + decoder + output head: 4 batch/block x 256 blocks = 1024
  k_seq5<<<256, 512, 0, stream>>>(ws + GX0, ws + GX1, ws + W_ENC, ws + W_DEC,
                                  ws + B_DEC, ow, ob, out);
}

// Round 8
// 408.685 us; speedup vs baseline: 8.2324x; 1.1733x over previous
//
#include <hip/hip_runtime.h>
#include <hip/hip_bf16.h>
#include <hip/hip_fp16.h>

// ---------------- problem constants ----------------
constexpr int GT = 32768;          // B*T frames
constexpr int TSEQ = 32;

typedef _Float16 h2 __attribute__((ext_vector_type(2)));

#if defined(__has_builtin)
#if __has_builtin(__builtin_amdgcn_fdot2)
#define FDOT2(a, b, c) __builtin_amdgcn_fdot2((a), (b), (c), false)
#endif
#endif
#ifndef FDOT2
#define FDOT2(a, b, c) fmaf((float)(a).x, (float)(b).x, fmaf((float)(a).y, (float)(b).y, (c)))
#endif

__device__ __forceinline__ h2 pack2(float a, float b) {
  h2 v; v.x = (_Float16)a; v.y = (_Float16)b; return v;
}

// ---------------- workspace layout (4-byte slots) ----------------
// obsT fp32 [400][GT] @0 (dead after conv1)
// pool1h h2 [200][GT] @13107200 (8 co-pairs x 25 pos) (dead after conv2)
// pool2h h2 [64][GT]  @0          (q = co2*4+pos pairs) (dead after fc1)
// y1h    h2 [64][GT]  @2097152    (fc1 j-pairs) (dead after fc2)
// featsh h2 [32][GT]  @19660800   (fc2 j-pairs)
// gx     f32 [32][1024][512] @0   (16777216 slots; obsT/pool2h/y1h dead by then)
constexpr size_t OBS_T  = 0;
constexpr size_t POOL1H = 13107200;
constexpr size_t POOL2H = 0;
constexpr size_t Y1H    = 2097152;
constexpr size_t FEATSH = 19660800;
constexpr size_t GX     = 0;
constexpr size_t WB     = 26214400;         // weights region (98304 slots total)
constexpr size_t W_C1   = WB + 0;           // 576  fp32: conv1 wT [36][16]
constexpr size_t W_C2H  = WB + 576;         // 2304 h2: [(ci2*9+t9)][32 co], ci pairs
constexpr size_t W_F1H  = WB + 2880;        // 8192 h2: [q=co2*4+pos][128 j], BN folded
constexpr size_t B_F1   = WB + 11072;       // 128 fp32
constexpr size_t W_F2H  = WB + 11200;       // 4096 h2: [k2][64 j], BN folded
constexpr size_t B_F2   = WB + 15296;       // 64 fp32
constexpr size_t W_ENCXH= WB + 15360;       // 16384 h2: [k2 0..31][512 r], rows r=u*4+gate
constexpr size_t W_ENCHH= WB + 31744;       // 32768 h2: [k2 0..63][512 r]
constexpr size_t B_ENC  = WB + 64512;       // 512 fp32
constexpr size_t W_DECH = WB + 65024;       // 32768 h2: (dec_w_ih+dec_w_hh) [k2][512]
constexpr size_t B_DEC  = WB + 97792;       // 512 fp32
// total = 26,312,704 slots = 105.3 MB (< R1's 107.2 MB which fit)

__device__ __forceinline__ float sigf(float x)  { return 1.f / (1.f + __expf(-x)); }
__device__ __forceinline__ float tanhfast(float x) { return 1.f - 2.f / (__expf(2.f * x) + 1.f); }

// ---------------- setup: transpose/fold/f16-pack weights (98304 items) ----------
__global__ __launch_bounds__(256) void k_setup(
    const float* __restrict__ c1w, const float* __restrict__ c2w,
    const float* __restrict__ f1w, const float* __restrict__ f1b,
    const float* __restrict__ g1, const float* __restrict__ be1,
    const float* __restrict__ m1, const float* __restrict__ v1,
    const float* __restrict__ f2w, const float* __restrict__ f2b,
    const float* __restrict__ g2, const float* __restrict__ be2,
    const float* __restrict__ m2, const float* __restrict__ v2,
    const float* __restrict__ ewih, const float* __restrict__ ewhh, const float* __restrict__ eb,
    const float* __restrict__ dwih, const float* __restrict__ dwhh, const float* __restrict__ db,
    float* __restrict__ ws) {
  h2* wsh = (h2*)ws;
  long i = (long)blockIdx.x * 256 + threadIdx.x;
  if (i < 576)  { int c = i & 15, r = i >> 4; ws[W_C1 + i] = c1w[c * 36 + r]; return; }
  i -= 576;
  if (i < 2304) { int co = i & 31, q = i >> 5; int ci2 = q / 9, t9 = q % 9;
    wsh[W_C2H + i] = pack2(c2w[co * 144 + (2 * ci2) * 9 + t9],
                           c2w[co * 144 + (2 * ci2 + 1) * 9 + t9]); return; }
  i -= 2304;
  if (i < 8192) { int j = i & 127, q = i >> 7; int co2 = q >> 2, pos = q & 3;
    float s = g1[j] * rsqrtf(v1[j] + 1e-5f);
    wsh[W_F1H + i] = pack2(f1w[j * 128 + 8 * co2 + pos] * s,
                           f1w[j * 128 + 8 * co2 + 4 + pos] * s); return; }
  i -= 8192;
  if (i < 128) { int j = i; float s = g1[j] * rsqrtf(v1[j] + 1e-5f);
    ws[B_F1 + i] = (f1b[j] - m1[j]) * s + be1[j]; return; }
  i -= 128;
  if (i < 4096) { int j = i & 63, k2 = i >> 6;
    float s = g2[j] * rsqrtf(v2[j] + 1e-5f);
    wsh[W_F2H + i] = pack2(f2w[j * 128 + 2 * k2] * s,
                           f2w[j * 128 + 2 * k2 + 1] * s); return; }
  i -= 4096;
  if (i < 64) { int j = i; float s = g2[j] * rsqrtf(v2[j] + 1e-5f);
    ws[B_F2 + i] = (f2b[j] - m2[j]) * s + be2[j]; return; }
  i -= 64;
  if (i < 16384) { int r = i & 511, k2 = i >> 9;
    int u = r >> 2, gt = r & 3, jr = gt * 128 + u;
    wsh[W_ENCXH + i] = pack2(ewih[jr * 64 + 2 * k2], ewih[jr * 64 + 2 * k2 + 1]); return; }
  i -= 16384;
  if (i < 32768) { int r = i & 511, k2 = i >> 9;
    int u = r >> 2, gt = r & 3, jr = gt * 128 + u;
    wsh[W_ENCHH + i] = pack2(ewhh[jr * 128 + 2 * k2], ewhh[jr * 128 + 2 * k2 + 1]); return; }
  i -= 32768;
  if (i < 512) { int u = i >> 2, gt = i & 3; ws[B_ENC + i] = eb[gt * 128 + u]; return; }
  i -= 512;
  if (i < 32768) { int r = i & 511, k2 = i >> 9;
    int u = r >> 2, gt = r & 3, jr = gt * 128 + u;
    wsh[W_DECH + i] = pack2(dwih[jr * 128 + 2 * k2] + dwhh[jr * 128 + 2 * k2],
                            dwih[jr * 128 + 2 * k2 + 1] + dwhh[jr * 128 + 2 * k2 + 1]); return; }
  i -= 32768;
  if (i < 512) { int u = i >> 2, gt = i & 3; ws[B_DEC + i] = db[gt * 128 + u]; return; }
}

// ---------------- transpose obs [b][tp] -> obsT [p][t][b], float4 loads ----------------
__global__ __launch_bounds__(256) void k_transpose(const float* __restrict__ obs,
                                                   float* __restrict__ obsT) {
  __shared__ float tile[64][65];
  int tp0 = blockIdx.x * 64;
  int b0  = blockIdx.y * 64;
  int q     = threadIdx.x & 15;
  int rbase = threadIdx.x >> 4;
  #pragma unroll
  for (int rr = 0; rr < 4; ++rr) {
    int row = rbase + rr * 16;
    const float4 v = *(const float4*)(obs + (size_t)(b0 + row) * 12800 + tp0 + q * 4);
    tile[row][q * 4 + 0] = v.x;
    tile[row][q * 4 + 1] = v.y;
    tile[row][q * 4 + 2] = v.z;
    tile[row][q * 4 + 3] = v.w;
  }
  __syncthreads();
  int lane = threadIdx.x & 63;
  int grp  = threadIdx.x >> 6;
  for (int cc = 0; cc < 16; ++cc) {
    int col = grp * 16 + cc;
    int tp = tp0 + col;
    int t = tp / 400, p = tp % 400;
    obsT[(size_t)p * GT + t * 1024 + b0 + lane] = tile[lane][col];
  }
}

// ---------------- conv1 (4->16, fp32 math) + relu + maxpool2; writes f16 co-pairs ----
__global__ __launch_bounds__(256) void k_conv1(const float* __restrict__ obsT,
                                               const float* __restrict__ wT,
                                               const float* __restrict__ bias,
                                               h2* __restrict__ pool1h) {
  int g = blockIdx.x * 256 + threadIdx.x;
  int pos = blockIdx.y;
  int py = pos / 5, px = pos % 5;
  float acc[4][16];
  #pragma unroll
  for (int s = 0; s < 4; ++s)
    #pragma unroll
    for (int c = 0; c < 16; ++c) acc[s][c] = 0.f;

  #pragma unroll 1
  for (int ci = 0; ci < 4; ++ci) {
    float p[16];
    #pragma unroll
    for (int r = 0; r < 4; ++r) {
      int iy = 2 * py + r - 1;
      #pragma unroll
      for (int cx = 0; cx < 4; ++cx) {
        int ix = 2 * px + cx - 1;
        bool ok = ((unsigned)iy < 10u) && ((unsigned)ix < 10u);   // wave-uniform
        p[r * 4 + cx] = ok ? obsT[(size_t)(ci * 100 + iy * 10 + ix) * GT + g] : 0.f;
      }
    }
    #pragma unroll
    for (int t9 = 0; t9 < 9; ++t9) {
      int ky = t9 / 3, kx = t9 % 3;
      const float* w = wT + ((ci * 9 + t9) << 4);
      float wv[16];
      #pragma unroll
      for (int c = 0; c < 16; ++c) wv[c] = w[c];
      #pragma unroll
      for (int dy = 0; dy < 2; ++dy)
        #pragma unroll
        for (int dx = 0; dx < 2; ++dx) {
          float xv = p[(dy + ky) * 4 + (dx + kx)];
          #pragma unroll
          for (int c = 0; c < 16; ++c)
            acc[dy * 2 + dx][c] = fmaf(wv[c], xv, acc[dy * 2 + dx][c]);
        }
    }
  }
  float m[16];
  #pragma unroll
  for (int c = 0; c < 16; ++c) {
    float v = fmaxf(fmaxf(acc[0][c], acc[1][c]), fmaxf(acc[2][c], acc[3][c]));
    m[c] = fmaxf(v + bias[c], 0.f);
  }
  #pragma unroll
  for (int c2 = 0; c2 < 8; ++c2)
    pool1h[(size_t)(c2 * 25 + pos) * GT + g] = pack2(m[2 * c2], m[2 * c2 + 1]);
}

// ---------------- conv2 (16->32) via f16 dot2 over ci-pairs; writes q=co2*4+pos ------
__global__ __launch_bounds__(256) void k_conv2h(const h2* __restrict__ pool1h,
                                                const h2* __restrict__ wch,
                                                const float* __restrict__ bias,
                                                h2* __restrict__ pool2h) {
  int g = blockIdx.x * 256 + threadIdx.x;
  int pos = blockIdx.y & 3;
  int h = blockIdx.y >> 2;              // co quarter (0..3), 8 channels each
  int py = pos >> 1, px = pos & 1;
  float acc[4][8];
  #pragma unroll
  for (int s = 0; s < 4; ++s)
    #pragma unroll
    for (int c = 0; c < 8; ++c) acc[s][c] = 0.f;
  const h2 hz = pack2(0.f, 0.f);

  #pragma unroll 1
  for (int ci2 = 0; ci2 < 8; ++ci2) {
    h2 p[16];
    #pragma unroll
    for (int r = 0; r < 4; ++r) {
      int iy = 2 * py + r - 1;
      #pragma unroll
      for (int cx = 0; cx < 4; ++cx) {
        int ix = 2 * px + cx - 1;
        bool ok = ((unsigned)iy < 5u) && ((unsigned)ix < 5u);     // wave-uniform
        p[r * 4 + cx] = ok ? pool1h[(size_t)(ci2 * 25 + iy * 5 + ix) * GT + g] : hz;
      }
    }
    #pragma unroll
    for (int t9 = 0; t9 < 9; ++t9) {
      int ky = t9 / 3, kx = t9 % 3;
      const h2* w = wch + (ci2 * 9 + t9) * 32 + h * 8;
      h2 wv[8];
      #pragma unroll
      for (int c = 0; c < 8; ++c) wv[c] = w[c];
      #pragma unroll
      for (int dy = 0; dy < 2; ++dy)
        #pragma unroll
        for (int dx = 0; dx < 2; ++dx) {
          h2 xv = p[(dy + ky) * 4 + (dx + kx)];
          #pragma unroll
          for (int c = 0; c < 8; ++c)
            acc[dy * 2 + dx][c] = FDOT2(xv, wv[c], acc[dy * 2 + dx][c]);
        }
    }
  }
  float m[8];
  #pragma unroll
  for (int c = 0; c < 8; ++c) {
    float v = fmaxf(fmaxf(acc[0][c], acc[1][c]), fmaxf(acc[2][c], acc[3][c]));
    m[c] = fmaxf(v + bias[h * 8 + c], 0.f);
  }
  #pragma unroll
  for (int c2 = 0; c2 < 4; ++c2) {
    int q = (h * 4 + c2) * 4 + pos;     // co2*4 + pos
    pool2h[(size_t)q * GT + g] = pack2(m[2 * c2], m[2 * c2 + 1]);
  }
}

// ---------------- FC via f16 dot2 (+folded BN) + relu; writes packed j-pairs --------
__global__ __launch_bounds__(256) void k_fc16h(const h2* __restrict__ x,
                                               const h2* __restrict__ WT,
                                               const float* __restrict__ bf,
                                               h2* __restrict__ y, int K2, int J) {
  int g = blockIdx.x * 256 + threadIdx.x;
  int j0 = blockIdx.y * 16;
  float acc[16];
  #pragma unroll
  for (int c = 0; c < 16; ++c) acc[c] = 0.f;
  for (int k2 = 0; k2 < K2; ++k2) {
    h2 xv = x[(size_t)k2 * GT + g];
    const h2* w = WT + (size_t)k2 * J + j0;
    #pragma unroll
    for (int c = 0; c < 16; ++c) acc[c] = FDOT2(xv, w[c], acc[c]);
  }
  #pragma unroll
  for (int c2 = 0; c2 < 8; ++c2) {
    float a = fmaxf(acc[2 * c2] + bf[j0 + 2 * c2], 0.f);
    float b = fmaxf(acc[2 * c2 + 1] + bf[j0 + 2 * c2 + 1], 0.f);
    y[(size_t)(j0 / 2 + c2) * GT + g] = pack2(a, b);
  }
}

// ---------------- encoder x-projection, f16 dot2; gx fp32 [t][b][512] ----------------
__global__ __launch_bounds__(256) void k_xgatesh(const h2* __restrict__ featsh,
                                                 const h2* __restrict__ wxh,
                                                 const float* __restrict__ br,
                                                 float* __restrict__ gx) {
  int t  = blockIdx.x >> 2;
  int bq = blockIdx.x & 3;
  int b  = bq * 256 + threadIdx.x;
  int r0 = blockIdx.y * 32;
  float acc[32];
  #pragma unroll
  for (int i = 0; i < 32; ++i) acc[i] = br[r0 + i];
  const h2* xcol = featsh + (size_t)t * 1024 + b;
  for (int k2 = 0; k2 < 32; ++k2) {
    h2 xv = xcol[(size_t)k2 * GT];
    const h2* w = wxh + k2 * 512 + r0;
    #pragma unroll
    for (int i = 0; i < 32; ++i) acc[i] = FDOT2(xv, w[i], acc[i]);
  }
  float* gxs = gx + (size_t)t * 524288 + (size_t)b * 512 + r0;
  #pragma unroll
  for (int i = 0; i < 32; ++i) gxs[i] = acc[i];
}

// ---------------- fused enc+dec+head, f16x2 register weights, 8-way k-split ---------
// 256 blocks x 512 threads, 4 batch/block (256*4 = 1024). Thread (kg=tid&7, g=tid>>3):
// gate rows r0=g*8..+7, k-pair slice [kg*8, kg*8+8) -> 64 weight h2 VGPRs (vs 128 fp32
// in R7 that overflowed into AGPRs). Per step: 4 bl x 8 r x 8 pairs = 256 dot2.
// Reduce: 3 shuffle rounds (xor1 sel kg&1, xor2 sel kg&2, xor4) -> lane kg holds full
// gates for bl=kg&3. h in LDS as packed f16 pairs (stride 68 -> <=2-way banks = free).
__global__ __launch_bounds__(512, 2) void k_seq6(
    const float* __restrict__ gx,
    const h2* __restrict__ WENCH, const h2* __restrict__ WDECH,
    const float* __restrict__ bdec,
    const float* __restrict__ ow, const float* __restrict__ ob,
    float* __restrict__ out) {
  const int tid = threadIdx.x;
  const int kg  = tid & 7;            // k-slice lane
  const int g   = tid >> 3;           // 0..63 row group (also h-pair index it produces)
  const int r0  = g * 8;
  const int blo = kg & 3;             // batch elem this lane finalizes
  const int bown = blockIdx.x * 4 + blo;

  __shared__ h2 hbufh[2][4 * 68];     // [buf][bl*68 + k2]
  __shared__ h2 owl2[12 * 68];        // packed out_w rows

  for (int i = tid; i < 2 * 4 * 68; i += 512) hbufh[0][i] = pack2(0.f, 0.f);
  for (int i = tid; i < 768; i += 512) {
    int o = i >> 6, k2 = i & 63;
    owl2[o * 68 + k2] = pack2(ow[o * 128 + 2 * k2], ow[o * 128 + 2 * k2 + 1]);
  }
  const float obv = (tid < 48) ? ob[tid >> 2] : 0.f;

  // ---- encoder h-part weight slice -> registers (once) ----
  h2 wreg[64];                        // wreg[p*8+r] = W[(kg*8+p)][r0+r]
  #pragma unroll
  for (int p = 0; p < 8; ++p) {
    const h2* wp = WENCH + (size_t)(kg * 8 + p) * 512 + r0;
    *(uint4*)&wreg[p * 8]     = *(const uint4*)wp;
    *(uint4*)&wreg[p * 8 + 4] = *(const uint4*)(wp + 4);
  }

  float c0 = 0.f, c1 = 0.f;
  const int rdofs = kg * 8;                     // k2-slice base within a bl row
  const int wrofs = blo * 68 + g;               // h2 write addr (pair g), lanes kg<4
  __syncthreads();

  int cur = 0;

  // ================= encoder: 32 steps =================
  for (int t = 0; t < TSEQ; ++t) {
    const float* gb0 = gx + (size_t)t * 524288 + (size_t)bown * 512 + r0;
    const float4 ga = *(const float4*)gb0;
    const float4 gb = *(const float4*)(gb0 + 4);

    float acc[4][8];
    #pragma unroll
    for (int bl = 0; bl < 4; ++bl)
      #pragma unroll
      for (int r = 0; r < 8; ++r) acc[bl][r] = 0.f;

    const h2* hc = &hbufh[cur][0];
    #pragma unroll
    for (int bl = 0; bl < 4; ++bl) {
      h2 hv[8];
      *(uint4*)&hv[0] = *(const uint4*)&hc[bl * 68 + rdofs];
      *(uint4*)&hv[4] = *(const uint4*)&hc[bl * 68 + rdofs + 4];
      #pragma unroll
      for (int p = 0; p < 8; ++p) {
        #pragma unroll
        for (int r = 0; r < 8; ++r)
          acc[bl][r] = FDOT2(hv[p], wreg[p * 8 + r], acc[bl][r]);
      }
    }
    // ---- 8-lane reduce with batch routing ----
    float D[8];
    #pragma unroll
    for (int r = 0; r < 8; ++r) {
      float a0 = acc[0][r] + __shfl_xor(acc[0][r], 1, 64);
      float a1 = acc[1][r] + __shfl_xor(acc[1][r], 1, 64);
      float a2 = acc[2][r] + __shfl_xor(acc[2][r], 1, 64);
      float a3 = acc[3][r] + __shfl_xor(acc[3][r], 1, 64);
      float sL = (kg & 1) ? a1 : a0;
      float sH = (kg & 1) ? a3 : a2;
      float tL = sL + __shfl_xor(sL, 2, 64);
      float tH = sH + __shfl_xor(sH, 2, 64);
      float s  = (kg & 2) ? tH : tL;
      s += __shfl_xor(s, 4, 64);
      D[r] = s;
    }
    const float gi0 = D[0] + ga.x, gf0 = D[1] + ga.y, gg0 = D[2] + ga.z, go0 = D[3] + ga.w;
    const float gi1 = D[4] + gb.x, gf1 = D[5] + gb.y, gg1 = D[6] + gb.z, go1 = D[7] + gb.w;
    c0 = sigf(gf0) * c0 + sigf(gi0) * tanhfast(gg0);
    c1 = sigf(gf1) * c1 + sigf(gi1) * tanhfast(gg1);
    const float hn0 = sigf(go0) * tanhfast(c0);
    const float hn1 = sigf(go1) * tanhfast(c1);
    if (kg < 4) hbufh[cur ^ 1][wrofs] = pack2(hn0, hn1);
    __syncthreads();
    cur ^= 1;
  }

  // ---- swap in decoder weights (x_in == h => W = W_ih + W_hh, pre-summed) ----
  #pragma unroll
  for (int p = 0; p < 8; ++p) {
    const h2* wp = WDECH + (size_t)(kg * 8 + p) * 512 + r0;
    *(uint4*)&wreg[p * 8]     = *(const uint4*)wp;
    *(uint4*)&wreg[p * 8 + 4] = *(const uint4*)(wp + 4);
  }
  const float4 bda = *(const float4*)(bdec + r0);
  const float4 bdb = *(const float4*)(bdec + r0 + 4);

  // ================= decoder: 10 steps + fused head =================
  for (int t = 0; t < 10; ++t) {
    float acc[4][8];
    #pragma unroll
    for (int bl = 0; bl < 4; ++bl)
      #pragma unroll
      for (int r = 0; r < 8; ++r) acc[bl][r] = 0.f;

    const h2* hc = &hbufh[cur][0];
    #pragma unroll
    for (int bl = 0; bl < 4; ++bl) {
      h2 hv[8];
      *(uint4*)&hv[0] = *(const uint4*)&hc[bl * 68 + rdofs];
      *(uint4*)&hv[4] = *(const uint4*)&hc[bl * 68 + rdofs + 4];
      #pragma unroll
      for (int p = 0; p < 8; ++p) {
        #pragma unroll
        for (int r = 0; r < 8; ++r)
          acc[bl][r] = FDOT2(hv[p], wreg[p * 8 + r], acc[bl][r]);
      }
    }
    float D[8];
    #pragma unroll
    for (int r = 0; r < 8; ++r) {
      float a0 = acc[0][r] + __shfl_xor(acc[0][r], 1, 64);
      float a1 = acc[1][r] + __shfl_xor(acc[1][r], 1, 64);
      float a2 = acc[2][r] + __shfl_xor(acc[2][r], 1, 64);
      float a3 = acc[3][r] + __shfl_xor(acc[3][r], 1, 64);
      float sL = (kg & 1) ? a1 : a0;
      float sH = (kg & 1) ? a3 : a2;
      float tL = sL + __shfl_xor(sL, 2, 64);
      float tH = sH + __shfl_xor(sH, 2, 64);
      float s  = (kg & 2) ? tH : tL;
      s += __shfl_xor(s, 4, 64);
      D[r] = s;
    }
    const float gi0 = D[0] + bda.x, gf0 = D[1] + bda.y, gg0 = D[2] + bda.z, go0 = D[3] + bda.w;
    const float gi1 = D[4] + bdb.x, gf1 = D[5] + bdb.y, gg1 = D[6] + bdb.z, go1 = D[7] + bdb.w;
    c0 = sigf(gf0) * c0 + sigf(gi0) * tanhfast(gg0);
    c1 = sigf(gf1) * c1 + sigf(gi1) * tanhfast(gg1);
    const float hn0 = sigf(go0) * tanhfast(c0);
    const float hn1 = sigf(go1) * tanhfast(c1);
    if (kg < 4) hbufh[cur ^ 1][wrofs] = pack2(hn0, hn1);
    __syncthreads();
    cur ^= 1;
    // output head: tid<48 (o = tid>>2, bl = tid&3), LDS-only reads of new h
    if (tid < 48) {
      const int o  = tid >> 2;
      const int bh = tid & 3;
      const h2* hh = &hbufh[cur][bh * 68];
      const h2* wo = &owl2[o * 68];
      float oacc = obv;
      #pragma unroll
      for (int k2 = 0; k2 < 64; ++k2) oacc = FDOT2(hh[k2], wo[k2], oacc);
      out[(blockIdx.x * 4 + bh) * 120 + t * 12 + o] = oacc;
    }
  }
}

// ---------------- launch ----------------
extern "C" void kernel_launch(void* const* d_in, const int* in_sizes, int n_in,
                              void* d_out, int out_size, void* d_ws, size_t ws_size,
                              hipStream_t stream) {
  const float* obs  = (const float*)d_in[0];
  const float* c1w  = (const float*)d_in[1];
  const float* c1b  = (const float*)d_in[2];
  const float* c2w  = (const float*)d_in[3];
  const float* c2b  = (const float*)d_in[4];
  const float* f1w  = (const float*)d_in[5];
  const float* f1b  = (const float*)d_in[6];
  const float* g1   = (const float*)d_in[7];
  const float* be1  = (const float*)d_in[8];
  const float* m1   = (const float*)d_in[9];
  const float* v1   = (const float*)d_in[10];
  const float* f2w  = (const float*)d_in[11];
  const float* f2b  = (const float*)d_in[12];
  const float* g2   = (const float*)d_in[13];
  const float* be2  = (const float*)d_in[14];
  const float* m2   = (const float*)d_in[15];
  const float* v2   = (const float*)d_in[16];
  const float* ewih = (const float*)d_in[17];
  const float* ewhh = (const float*)d_in[18];
  const float* eb   = (const float*)d_in[19];
  const float* dwih = (const float*)d_in[20];
  const float* dwhh = (const float*)d_in[21];
  const float* db   = (const float*)d_in[22];
  const float* ow   = (const float*)d_in[23];
  const float* ob   = (const float*)d_in[24];
  float* ws  = (float*)d_ws;
  h2*    wsh = (h2*)d_ws;
  float* out = (float*)d_out;

  // weight prep: 98304 items = 384 blocks x 256
  k_setup<<<384, 256, 0, stream>>>(c1w, c2w, f1w, f1b, g1, be1, m1, v1,
                                   f2w, f2b, g2, be2, m2, v2,
                                   ewih, ewhh, eb, dwih, dwhh, db, ws);
  k_transpose<<<dim3(200, 16), 256, 0, stream>>>(obs, ws + OBS_T);
  k_conv1<<<dim3(128, 25), 256, 0, stream>>>(ws + OBS_T, ws + W_C1, c1b, wsh + POOL1H);
  k_conv2h<<<dim3(128, 16), 256, 0, stream>>>(wsh + POOL1H, wsh + W_C2H, c2b, wsh + POOL2H);
  k_fc16h<<<dim3(128, 8), 256, 0, stream>>>(wsh + POOL2H, wsh + W_F1H, ws + B_F1,
                                            wsh + Y1H, 64, 128);
  k_fc16h<<<dim3(128, 4), 256, 0, stream>>>(wsh + Y1H, wsh + W_F2H, ws + B_F2,
                                            wsh + FEATSH, 64, 64);
  k_xgatesh<<<dim3(128, 16), 256, 0, stream>>>(wsh + FEATSH, wsh + W_ENCXH, ws + B_ENC,
                                               ws + GX);
  // fused encoder + decoder + output head: f16x2 register-resident weights
  k_seq6<<<256, 512, 0, stream>>>(ws + GX, wsh + W_ENCHH, wsh + W_DECH,
                                  ws + B_DEC, ow, ob, out);
}